// Round 1
// baseline (763.742 us; speedup 1.0000x reference)
//
#include <hip/hip_runtime.h>

// GAT 2-layer + BN + final linear on MI355X.
// Strategy: CSR-by-dst built per launch (hist/scan/fill), BN folded into GEMM
// A-loads as per-channel affine (+ELU where needed), wave-per-node softmax,
// block-per-node aggregation (no scatter atomics on the heavy path).

#define NEG_SLOPE 0.2f
#define BN_EPS 1e-5f

// ---------------- CSR build ----------------
__global__ void k_hist(const int* __restrict__ ei, int E, int Nn, int* __restrict__ cnt) {
    int i = blockIdx.x * blockDim.x + threadIdx.x;
    if (i >= E + Nn) return;
    int d = (i < E) ? ei[E + i] : (i - E);   // row 1 of edge_index = dst; self-loops appended
    atomicAdd(&cnt[d], 1);
}

__global__ __launch_bounds__(1024) void k_scan(const int* __restrict__ cnt, int Nn,
                                               int* __restrict__ rowptr, int* __restrict__ cursor) {
    __shared__ int wsum[16];
    __shared__ int s_carry, s_tile;
    int t = threadIdx.x, lane = t & 63, w = t >> 6;
    if (t == 0) s_carry = 0;
    __syncthreads();
    for (int base = 0; base < Nn; base += 1024) {
        int i = base + t;
        int v = (i < Nn) ? cnt[i] : 0;
        int x = v;
        #pragma unroll
        for (int off = 1; off < 64; off <<= 1) {
            int y = __shfl_up(x, off);
            if (lane >= off) x += y;
        }
        if (lane == 63) wsum[w] = x;
        __syncthreads();
        int carry = s_carry;
        if (w == 0) {
            int val = (lane < 16) ? wsum[lane] : 0;
            int xs = val;
            #pragma unroll
            for (int off = 1; off < 64; off <<= 1) {
                int y = __shfl_up(xs, off);
                if (lane >= off) xs += y;
            }
            if (lane == 15) s_tile = xs;             // tile total
            if (lane < 16) wsum[lane] = xs - val;    // exclusive wave offsets
        }
        __syncthreads();
        if (i < Nn) {
            int pos = carry + wsum[w] + (x - v);
            rowptr[i] = pos;
            cursor[i] = pos;
        }
        __syncthreads();
        if (t == 0) s_carry = carry + s_tile;
        __syncthreads();
    }
    if (threadIdx.x == 0) rowptr[Nn] = s_carry;
}

__global__ void k_fill(const int* __restrict__ ei, int E, int Nn,
                       int* __restrict__ cursor, int* __restrict__ ssrc) {
    int i = blockIdx.x * blockDim.x + threadIdx.x;
    if (i >= E + Nn) return;
    int s, d;
    if (i < E) { s = ei[i]; d = ei[E + i]; }
    else       { s = i - E; d = s; }
    int pos = atomicAdd(&cursor[d], 1);
    ssrc[pos] = s;
}

// ---------------- BatchNorm stats ----------------
// blockDim == C (64 or 128); each block handles `rows` rows; coalesced row reads.
__global__ void k_bnstat(const float* __restrict__ x, int M, int C, int rows,
                         float* __restrict__ sums) {
    int c = threadIdx.x;
    int r0 = blockIdx.x * rows;
    int r1 = min(M, r0 + rows);
    float s = 0.f, s2 = 0.f;
    for (int r = r0; r < r1; r++) {
        float v = x[(size_t)r * C + c];
        s += v; s2 += v * v;
    }
    atomicAdd(&sums[c], s);
    atomicAdd(&sums[C + c], s2);
}

__global__ void k_bnfin(const float* __restrict__ sums, int M, int C,
                        const float* __restrict__ g, const float* __restrict__ b,
                        float* __restrict__ st) {
    int c = threadIdx.x;
    if (c < C) {
        float mu = sums[c] / (float)M;
        float var = sums[C + c] / (float)M - mu * mu;
        float s = g[c] * rsqrtf(var + BN_EPS);
        st[c] = s;
        st[C + c] = b[c] - mu * s;
    }
}

// ---------------- GEMM [M,128] @ [128,128], BN affine (+optional ELU) fused on A ----------------
// BM=128 rows, BN=64 cols (blockIdx.y), BK=32; 256 threads, 8x4 per-thread tile.
__global__ __launch_bounds__(256) void k_gemm128(
    const float* __restrict__ A, const float* __restrict__ W,
    const float* __restrict__ st, int M, int elu, float* __restrict__ out) {
    __shared__ float As[128 * 33];   // +1 pad: conflict-free staging writes
    __shared__ float Bs[32 * 64];
    const int t = threadIdx.x;
    const int row0 = blockIdx.x * 128;
    const int col0 = blockIdx.y * 64;
    const int cg = t & 15, rg = t >> 4;
    float acc[8][4] = {};
    for (int k0 = 0; k0 < 128; k0 += 32) {
        #pragma unroll
        for (int i = 0; i < 16; i++) {           // A tile: 128x32
            int idx = t + i * 256;
            int r = idx >> 5, k = idx & 31;
            int gr = row0 + r;
            float v = 0.f;
            if (gr < M) {
                int ch = k0 + k;
                v = A[(size_t)gr * 128 + ch] * st[ch] + st[128 + ch];
                if (elu) v = v > 0.f ? v : expm1f(v);
            }
            As[r * 33 + k] = v;
        }
        #pragma unroll
        for (int i = 0; i < 8; i++) {            // B tile: 32x64
            int idx = t + i * 256;
            int k = idx >> 6, c = idx & 63;
            Bs[k * 64 + c] = W[(size_t)(k0 + k) * 128 + col0 + c];
        }
        __syncthreads();
        #pragma unroll
        for (int k = 0; k < 32; k++) {
            float4 b = *(const float4*)&Bs[k * 64 + cg * 4];
            #pragma unroll
            for (int j = 0; j < 8; j++) {
                float a = As[(rg * 8 + j) * 33 + k];
                acc[j][0] += a * b.x; acc[j][1] += a * b.y;
                acc[j][2] += a * b.z; acc[j][3] += a * b.w;
            }
        }
        __syncthreads();
    }
    #pragma unroll
    for (int j = 0; j < 8; j++) {
        int gr = row0 + rg * 8 + j;
        if (gr < M) {
            float4 v = make_float4(acc[j][0], acc[j][1], acc[j][2], acc[j][3]);
            *(float4*)&out[(size_t)gr * 128 + col0 + cg * 4] = v;
        }
    }
}

// ---------------- attention logits: wave per node ----------------
__global__ void k_al(const float* __restrict__ h, const float* __restrict__ asrc,
                     const float* __restrict__ adst, int M,
                     float* __restrict__ als, float* __restrict__ ald) {
    int g = blockIdx.x * blockDim.x + threadIdx.x;
    int w = g >> 6, lane = g & 63;
    if (w >= M) return;
    float h0 = h[(size_t)w * 128 + lane];
    float h1 = h[(size_t)w * 128 + 64 + lane];
    float s0 = h0 * asrc[lane];
    float s1 = h1 * asrc[64 + lane];
    float d0 = h0 * adst[lane];
    float d1 = h1 * adst[64 + lane];
    #pragma unroll
    for (int off = 32; off; off >>= 1) {
        s0 += __shfl_xor(s0, off);
        s1 += __shfl_xor(s1, off);
        d0 += __shfl_xor(d0, off);
        d1 += __shfl_xor(d1, off);
    }
    if (lane == 0) {
        als[w * 2] = s0; als[w * 2 + 1] = s1;
        ald[w * 2] = d0; ald[w * 2 + 1] = d1;
    }
}

// ---------------- segment softmax: wave per dst node ----------------
__global__ void k_attn(const int* __restrict__ rowptr, const int* __restrict__ ssrc,
                       const float* __restrict__ als, const float* __restrict__ ald,
                       int Nn, float* __restrict__ alpha) {
    int g = blockIdx.x * blockDim.x + threadIdx.x;
    int w = g >> 6, lane = g & 63;
    if (w >= Nn) return;
    int beg = rowptr[w], end = rowptr[w + 1];
    float d0 = ald[w * 2], d1 = ald[w * 2 + 1];
    float m0 = -1e30f, m1 = -1e30f;
    for (int e = beg + lane; e < end; e += 64) {
        int s = ssrc[e];
        float v0 = als[s * 2] + d0;     v0 = v0 > 0.f ? v0 : NEG_SLOPE * v0;
        float v1 = als[s * 2 + 1] + d1; v1 = v1 > 0.f ? v1 : NEG_SLOPE * v1;
        m0 = fmaxf(m0, v0); m1 = fmaxf(m1, v1);
    }
    #pragma unroll
    for (int off = 32; off; off >>= 1) {
        m0 = fmaxf(m0, __shfl_xor(m0, off));
        m1 = fmaxf(m1, __shfl_xor(m1, off));
    }
    float t0 = 0.f, t1 = 0.f;
    for (int e = beg + lane; e < end; e += 64) {
        int s = ssrc[e];
        float v0 = als[s * 2] + d0;     v0 = v0 > 0.f ? v0 : NEG_SLOPE * v0;
        float v1 = als[s * 2 + 1] + d1; v1 = v1 > 0.f ? v1 : NEG_SLOPE * v1;
        float p0 = __expf(v0 - m0), p1 = __expf(v1 - m1);
        alpha[e * 2] = p0; alpha[e * 2 + 1] = p1;
        t0 += p0; t1 += p1;
    }
    #pragma unroll
    for (int off = 32; off; off >>= 1) {
        t0 += __shfl_xor(t0, off);
        t1 += __shfl_xor(t1, off);
    }
    float i0 = 1.f / t0, i1 = 1.f / t1;
    for (int e = beg + lane; e < end; e += 64) {
        alpha[e * 2]     *= i0;
        alpha[e * 2 + 1] *= i1;
    }
}

// ---------------- aggregation: block per dst node ----------------
__global__ __launch_bounds__(128) void k_agg1(const int* __restrict__ rowptr, const int* __restrict__ ssrc,
                                              const float* __restrict__ alpha, const float* __restrict__ h,
                                              const float* __restrict__ bias, int Nn, float* __restrict__ out) {
    int n = blockIdx.x;
    int c = threadIdx.x;
    int head = c >> 6;
    int beg = rowptr[n], end = rowptr[n + 1];
    float acc = 0.f;
    for (int e = beg; e < end; e++) {
        int s = ssrc[e];                 // block-uniform -> scalar load
        float a = alpha[e * 2 + head];
        acc += a * h[(size_t)s * 128 + c];   // 512B coalesced gather
    }
    out[(size_t)n * 128 + c] = acc + bias[c];
}

__global__ __launch_bounds__(64) void k_agg2(const int* __restrict__ rowptr, const int* __restrict__ ssrc,
                                             const float* __restrict__ alpha, const float* __restrict__ h,
                                             const float* __restrict__ bias, int Nn, float* __restrict__ out) {
    int n = blockIdx.x;
    int c = threadIdx.x;
    int beg = rowptr[n], end = rowptr[n + 1];
    float a0 = 0.f, a1 = 0.f;
    for (int e = beg; e < end; e++) {
        int s = ssrc[e];
        a0 += alpha[e * 2]     * h[(size_t)s * 128 + c];
        a1 += alpha[e * 2 + 1] * h[(size_t)s * 128 + 64 + c];
    }
    out[(size_t)n * 64 + c] = 0.5f * (a0 + a1) + bias[c];
}

// ---------------- final GEMM [M,64] @ [64,40] + bias, BN affine + ELU fused on A ----------------
__global__ __launch_bounds__(128) void k_gemmf(const float* __restrict__ A, const float* __restrict__ Wf,
                                               const float* __restrict__ bf, const float* __restrict__ st,
                                               int M, float* __restrict__ out) {
    __shared__ float As[128 * 65];
    __shared__ float Bs[64 * 40];
    int t = threadIdx.x;
    int row0 = blockIdx.x * 128;
    for (int i = t; i < 64 * 40; i += 128) Bs[i] = Wf[i];
    for (int i = t; i < 128 * 64; i += 128) {
        int r = i >> 6, k = i & 63;
        int gr = row0 + r;
        float v = 0.f;
        if (gr < M) {
            v = A[(size_t)gr * 64 + k] * st[k] + st[64 + k];
            v = v > 0.f ? v : expm1f(v);
        }
        As[r * 65 + k] = v;
    }
    __syncthreads();
    int cg = t & 3, rg = t >> 2;   // 4 colgroups x 10 cols, 32 rowgroups x 4 rows
    float acc[4][10] = {};
    for (int k = 0; k < 64; k++) {
        float b[10];
        #pragma unroll
        for (int j = 0; j < 10; j++) b[j] = Bs[k * 40 + cg * 10 + j];
        #pragma unroll
        for (int r = 0; r < 4; r++) {
            float a = As[(rg * 4 + r) * 65 + k];
            #pragma unroll
            for (int j = 0; j < 10; j++) acc[r][j] += a * b[j];
        }
    }
    for (int r = 0; r < 4; r++) {
        int gr = row0 + rg * 4 + r;
        if (gr < M) {
            #pragma unroll
            for (int j = 0; j < 10; j++) out[(size_t)gr * 40 + cg * 10 + j] = acc[r][j] + bf[cg * 10 + j];
        }
    }
}

extern "C" void kernel_launch(void* const* d_in, const int* in_sizes, int n_in,
                              void* d_out, int out_size, void* d_ws, size_t ws_size,
                              hipStream_t stream) {
    const float* x     = (const float*)d_in[0];
    const int*   ei    = (const int*)d_in[1];
    const float* bn0_g = (const float*)d_in[2];
    const float* bn0_b = (const float*)d_in[3];
    const float* W1    = (const float*)d_in[4];
    const float* a1s   = (const float*)d_in[5];
    const float* a1d   = (const float*)d_in[6];
    const float* b1    = (const float*)d_in[7];
    const float* bn1_g = (const float*)d_in[8];
    const float* bn1_b = (const float*)d_in[9];
    const float* W2    = (const float*)d_in[10];
    const float* a2s   = (const float*)d_in[11];
    const float* a2d   = (const float*)d_in[12];
    const float* b2    = (const float*)d_in[13];
    const float* bn2_g = (const float*)d_in[14];
    const float* bn2_b = (const float*)d_in[15];
    const float* Wf    = (const float*)d_in[16];
    const float* bf    = (const float*)d_in[17];
    float* out = (float*)d_out;

    const int N  = in_sizes[0] / 128;
    const int E  = in_sizes[1] / 2;
    const int ET = E + N;

    // workspace carve-up (~63 MB)
    char* ws = (char*)d_ws;
    size_t off = 0;
    auto alloc = [&](size_t bytes) -> char* {
        char* p = ws + off;
        off = (off + bytes + 255) & ~(size_t)255;
        return p;
    };
    int*   cnt    = (int*)alloc((size_t)N * 4);
    int*   rowptr = (int*)alloc((size_t)(N + 1) * 4);
    int*   cursor = (int*)alloc((size_t)N * 4);
    int*   ssrc   = (int*)alloc((size_t)ET * 4);
    float* alpha  = (float*)alloc((size_t)ET * 2 * 4);
    float* hbuf   = (float*)alloc((size_t)N * 128 * 4);
    float* abuf   = (float*)alloc((size_t)N * 128 * 4);
    float* als    = (float*)alloc((size_t)N * 2 * 4);
    float* ald    = (float*)alloc((size_t)N * 2 * 4);
    float* sums   = (float*)alloc(256 * 4);
    float* st     = (float*)alloc(256 * 4);

    const int tb = 256;
    const int egrid = (ET + tb - 1) / tb;
    const int wgrid = (N * 64 + tb - 1) / tb;   // wave-per-node kernels

    // CSR build (graph identical for both layers)
    hipMemsetAsync(cnt, 0, (size_t)N * 4, stream);
    k_hist<<<egrid, tb, 0, stream>>>(ei, E, N, cnt);
    k_scan<<<1, 1024, 0, stream>>>(cnt, N, rowptr, cursor);
    k_fill<<<egrid, tb, 0, stream>>>(ei, E, N, cursor, ssrc);

    // BN0 stats -> affine params
    hipMemsetAsync(sums, 0, 256 * 4, stream);
    k_bnstat<<<(N + 63) / 64, 128, 0, stream>>>(x, N, 128, 64, sums);
    k_bnfin<<<1, 128, 0, stream>>>(sums, N, 128, bn0_g, bn0_b, st);

    // layer 1
    dim3 g1((N + 127) / 128, 2);
    k_gemm128<<<g1, 256, 0, stream>>>(x, W1, st, N, 0, hbuf);
    k_al<<<wgrid, tb, 0, stream>>>(hbuf, a1s, a1d, N, als, ald);
    k_attn<<<wgrid, tb, 0, stream>>>(rowptr, ssrc, als, ald, N, alpha);
    k_agg1<<<N, 128, 0, stream>>>(rowptr, ssrc, alpha, hbuf, b1, N, abuf);

    // BN1
    hipMemsetAsync(sums, 0, 256 * 4, stream);
    k_bnstat<<<(N + 63) / 64, 128, 0, stream>>>(abuf, N, 128, 64, sums);
    k_bnfin<<<1, 128, 0, stream>>>(sums, N, 128, bn1_g, bn1_b, st);

    // layer 2 (ELU+BN fused into A-load)
    k_gemm128<<<g1, 256, 0, stream>>>(abuf, W2, st, N, 1, hbuf);
    k_al<<<wgrid, tb, 0, stream>>>(hbuf, a2s, a2d, N, als, ald);
    k_attn<<<wgrid, tb, 0, stream>>>(rowptr, ssrc, als, ald, N, alpha);
    k_agg2<<<N, 64, 0, stream>>>(rowptr, ssrc, alpha, hbuf, b2, N, abuf);

    // BN2
    hipMemsetAsync(sums, 0, 256 * 4, stream);
    k_bnstat<<<(N + 63) / 64, 64, 0, stream>>>(abuf, N, 64, 64, sums);
    k_bnfin<<<1, 64, 0, stream>>>(sums, N, 64, bn2_g, bn2_b, st);

    // final linear (BN2+ELU fused into A-load)
    k_gemmf<<<(N + 127) / 128, 128, 0, stream>>>(abuf, Wf, bf, st, N, out);
}

// Round 2
// 674.265 us; speedup vs baseline: 1.1327x; 1.1327x over previous
//
#include <hip/hip_runtime.h>

// GAT 2-layer + BN + final linear on MI355X.
// R2: bf16 h-gather (halves agg traffic), 2-wave edge-split + unroll-4 agg
// (MLP for the latency-bound gather chain), single-pass registerized segment
// softmax (deg<=64 fast path), k-major As in GEMM (ds_read_b128).

#define NEG_SLOPE 0.2f
#define BN_EPS 1e-5f

static __device__ __forceinline__ unsigned short f2bf(float f) {
    union { float f; unsigned u; } v; v.f = f;
    unsigned r = v.u + 0x7FFF + ((v.u >> 16) & 1);
    return (unsigned short)(r >> 16);
}
static __device__ __forceinline__ float2 bf2x2(unsigned v) {
    union { unsigned u; float f; } a, b;
    a.u = v << 16; b.u = v & 0xffff0000u;
    return make_float2(a.f, b.f);
}

// ---------------- CSR build ----------------
__global__ void k_hist(const int* __restrict__ ei, int E, int Nn, int* __restrict__ cnt) {
    int i = blockIdx.x * blockDim.x + threadIdx.x;
    if (i >= E + Nn) return;
    int d = (i < E) ? ei[E + i] : (i - E);
    atomicAdd(&cnt[d], 1);
}

__global__ __launch_bounds__(1024) void k_scan(const int* __restrict__ cnt, int Nn,
                                               int* __restrict__ rowptr, int* __restrict__ cursor) {
    __shared__ int wsum[16];
    __shared__ int s_carry, s_tile;
    int t = threadIdx.x, lane = t & 63, w = t >> 6;
    if (t == 0) s_carry = 0;
    __syncthreads();
    for (int base = 0; base < Nn; base += 1024) {
        int i = base + t;
        int v = (i < Nn) ? cnt[i] : 0;
        int x = v;
        #pragma unroll
        for (int off = 1; off < 64; off <<= 1) {
            int y = __shfl_up(x, off);
            if (lane >= off) x += y;
        }
        if (lane == 63) wsum[w] = x;
        __syncthreads();
        int carry = s_carry;
        if (w == 0) {
            int val = (lane < 16) ? wsum[lane] : 0;
            int xs = val;
            #pragma unroll
            for (int off = 1; off < 64; off <<= 1) {
                int y = __shfl_up(xs, off);
                if (lane >= off) xs += y;
            }
            if (lane == 15) s_tile = xs;
            if (lane < 16) wsum[lane] = xs - val;
        }
        __syncthreads();
        if (i < Nn) {
            int pos = carry + wsum[w] + (x - v);
            rowptr[i] = pos;
            cursor[i] = pos;
        }
        __syncthreads();
        if (t == 0) s_carry = carry + s_tile;
        __syncthreads();
    }
    if (threadIdx.x == 0) rowptr[Nn] = s_carry;
}

__global__ void k_fill(const int* __restrict__ ei, int E, int Nn,
                       int* __restrict__ cursor, int* __restrict__ ssrc) {
    int i = blockIdx.x * blockDim.x + threadIdx.x;
    if (i >= E + Nn) return;
    int s, d;
    if (i < E) { s = ei[i]; d = ei[E + i]; }
    else       { s = i - E; d = s; }
    int pos = atomicAdd(&cursor[d], 1);
    ssrc[pos] = s;
}

// ---------------- BatchNorm stats ----------------
__global__ void k_bnstat(const float* __restrict__ x, int M, int C, int rows,
                         float* __restrict__ sums) {
    int c = threadIdx.x;
    int r0 = blockIdx.x * rows;
    int r1 = min(M, r0 + rows);
    float s = 0.f, s2 = 0.f;
    for (int r = r0; r < r1; r++) {
        float v = x[(size_t)r * C + c];
        s += v; s2 += v * v;
    }
    atomicAdd(&sums[c], s);
    atomicAdd(&sums[C + c], s2);
}

__global__ void k_bnfin(const float* __restrict__ sums, int M, int C,
                        const float* __restrict__ g, const float* __restrict__ b,
                        float* __restrict__ st) {
    int c = threadIdx.x;
    if (c < C) {
        float mu = sums[c] / (float)M;
        float var = sums[C + c] / (float)M - mu * mu;
        float s = g[c] * rsqrtf(var + BN_EPS);
        st[c] = s;
        st[C + c] = b[c] - mu * s;
    }
}

// ---------------- GEMM [M,128] @ [128,128], BN affine (+optional ELU) fused on A ----------------
// BM=128, BN=64 (blockIdx.y), BK=32; 256 threads, 8x4/thread. As is k-major
// stride 132 (16B-aligned rows) so inner loop uses ds_read_b128.
__global__ __launch_bounds__(256) void k_gemm128(
    const float* __restrict__ A, const float* __restrict__ W,
    const float* __restrict__ st, int M, int elu,
    float* __restrict__ out, unsigned short* __restrict__ hb) {
    __shared__ float As[32 * 132];
    __shared__ float Bs[32 * 64];
    const int t = threadIdx.x;
    const int row0 = blockIdx.x * 128;
    const int col0 = blockIdx.y * 64;
    const int cg = t & 15, rg = t >> 4;
    float acc[8][4] = {};
    for (int k0 = 0; k0 < 128; k0 += 32) {
        #pragma unroll
        for (int i = 0; i < 16; i++) {           // A tile: 128 rows x 32 k
            int idx = t + i * 256;
            int k = idx & 31, r = idx >> 5;
            int gr = row0 + r;
            float v = 0.f;
            if (gr < M) {
                int ch = k0 + k;
                v = A[(size_t)gr * 128 + ch] * st[ch] + st[128 + ch];
                if (elu) v = v > 0.f ? v : expm1f(v);
            }
            As[k * 132 + r] = v;
        }
        #pragma unroll
        for (int i = 0; i < 8; i++) {            // B tile: 32 k x 64 cols
            int idx = t + i * 256;
            int k = idx >> 6, c = idx & 63;
            Bs[k * 64 + c] = W[(size_t)(k0 + k) * 128 + col0 + c];
        }
        __syncthreads();
        #pragma unroll
        for (int k = 0; k < 32; k++) {
            float4 b = *(const float4*)&Bs[k * 64 + cg * 4];
            float4 a0 = *(const float4*)&As[k * 132 + rg * 8];
            float4 a1 = *(const float4*)&As[k * 132 + rg * 8 + 4];
            acc[0][0] += a0.x * b.x; acc[0][1] += a0.x * b.y; acc[0][2] += a0.x * b.z; acc[0][3] += a0.x * b.w;
            acc[1][0] += a0.y * b.x; acc[1][1] += a0.y * b.y; acc[1][2] += a0.y * b.z; acc[1][3] += a0.y * b.w;
            acc[2][0] += a0.z * b.x; acc[2][1] += a0.z * b.y; acc[2][2] += a0.z * b.z; acc[2][3] += a0.z * b.w;
            acc[3][0] += a0.w * b.x; acc[3][1] += a0.w * b.y; acc[3][2] += a0.w * b.z; acc[3][3] += a0.w * b.w;
            acc[4][0] += a1.x * b.x; acc[4][1] += a1.x * b.y; acc[4][2] += a1.x * b.z; acc[4][3] += a1.x * b.w;
            acc[5][0] += a1.y * b.x; acc[5][1] += a1.y * b.y; acc[5][2] += a1.y * b.z; acc[5][3] += a1.y * b.w;
            acc[6][0] += a1.z * b.x; acc[6][1] += a1.z * b.y; acc[6][2] += a1.z * b.z; acc[6][3] += a1.z * b.w;
            acc[7][0] += a1.w * b.x; acc[7][1] += a1.w * b.y; acc[7][2] += a1.w * b.z; acc[7][3] += a1.w * b.w;
        }
        __syncthreads();
    }
    #pragma unroll
    for (int j = 0; j < 8; j++) {
        int gr = row0 + rg * 8 + j;
        if (gr < M) {
            float4 v = make_float4(acc[j][0], acc[j][1], acc[j][2], acc[j][3]);
            *(float4*)&out[(size_t)gr * 128 + col0 + cg * 4] = v;
            unsigned p0 = ((unsigned)f2bf(acc[j][1]) << 16) | f2bf(acc[j][0]);
            unsigned p1 = ((unsigned)f2bf(acc[j][3]) << 16) | f2bf(acc[j][2]);
            *(uint2*)&hb[(size_t)gr * 128 + col0 + cg * 4] = make_uint2(p0, p1);
        }
    }
}

// ---------------- attention logits: wave per node ----------------
__global__ void k_al(const float* __restrict__ h, const float* __restrict__ asrc,
                     const float* __restrict__ adst, int M,
                     float* __restrict__ als, float* __restrict__ ald) {
    int g = blockIdx.x * blockDim.x + threadIdx.x;
    int w = g >> 6, lane = g & 63;
    if (w >= M) return;
    float h0 = h[(size_t)w * 128 + lane];
    float h1 = h[(size_t)w * 128 + 64 + lane];
    float s0 = h0 * asrc[lane];
    float s1 = h1 * asrc[64 + lane];
    float d0 = h0 * adst[lane];
    float d1 = h1 * adst[64 + lane];
    #pragma unroll
    for (int off = 32; off; off >>= 1) {
        s0 += __shfl_xor(s0, off);
        s1 += __shfl_xor(s1, off);
        d0 += __shfl_xor(d0, off);
        d1 += __shfl_xor(d1, off);
    }
    if (lane == 0) {
        als[w * 2] = s0; als[w * 2 + 1] = s1;
        ald[w * 2] = d0; ald[w * 2 + 1] = d1;
    }
}

// ---------------- segment softmax: wave per dst node, single pass for deg<=64 ----------------
__global__ void k_attn(const int* __restrict__ rowptr, const int* __restrict__ ssrc,
                       const float* __restrict__ als, const float* __restrict__ ald,
                       int Nn, float* __restrict__ alpha) {
    int g = blockIdx.x * blockDim.x + threadIdx.x;
    int w = g >> 6, lane = g & 63;
    if (w >= Nn) return;
    int beg = rowptr[w], end = rowptr[w + 1];
    int deg = end - beg;
    float2 dv = *(const float2*)&ald[(size_t)w * 2];
    if (deg <= 64) {
        bool on = lane < deg;
        int e = beg + (on ? lane : 0);
        int s = ssrc[e];
        float2 av = *(const float2*)&als[(size_t)s * 2];
        float v0 = av.x + dv.x; v0 = v0 > 0.f ? v0 : NEG_SLOPE * v0;
        float v1 = av.y + dv.y; v1 = v1 > 0.f ? v1 : NEG_SLOPE * v1;
        float m0 = on ? v0 : -1e30f, m1 = on ? v1 : -1e30f;
        #pragma unroll
        for (int off = 32; off; off >>= 1) {
            m0 = fmaxf(m0, __shfl_xor(m0, off));
            m1 = fmaxf(m1, __shfl_xor(m1, off));
        }
        float p0 = on ? __expf(v0 - m0) : 0.f;
        float p1 = on ? __expf(v1 - m1) : 0.f;
        float t0 = p0, t1 = p1;
        #pragma unroll
        for (int off = 32; off; off >>= 1) {
            t0 += __shfl_xor(t0, off);
            t1 += __shfl_xor(t1, off);
        }
        if (on) *(float2*)&alpha[(size_t)e * 2] = make_float2(p0 / t0, p1 / t1);
    } else {
        float d0 = dv.x, d1 = dv.y;
        float m0 = -1e30f, m1 = -1e30f;
        for (int e = beg + lane; e < end; e += 64) {
            int s = ssrc[e];
            float v0 = als[s * 2] + d0;     v0 = v0 > 0.f ? v0 : NEG_SLOPE * v0;
            float v1 = als[s * 2 + 1] + d1; v1 = v1 > 0.f ? v1 : NEG_SLOPE * v1;
            m0 = fmaxf(m0, v0); m1 = fmaxf(m1, v1);
        }
        #pragma unroll
        for (int off = 32; off; off >>= 1) {
            m0 = fmaxf(m0, __shfl_xor(m0, off));
            m1 = fmaxf(m1, __shfl_xor(m1, off));
        }
        float t0 = 0.f, t1 = 0.f;
        for (int e = beg + lane; e < end; e += 64) {
            int s = ssrc[e];
            float v0 = als[s * 2] + d0;     v0 = v0 > 0.f ? v0 : NEG_SLOPE * v0;
            float v1 = als[s * 2 + 1] + d1; v1 = v1 > 0.f ? v1 : NEG_SLOPE * v1;
            float p0 = __expf(v0 - m0), p1 = __expf(v1 - m1);
            alpha[e * 2] = p0; alpha[e * 2 + 1] = p1;
            t0 += p0; t1 += p1;
        }
        #pragma unroll
        for (int off = 32; off; off >>= 1) {
            t0 += __shfl_xor(t0, off);
            t1 += __shfl_xor(t1, off);
        }
        float i0 = 1.f / t0, i1 = 1.f / t1;
        for (int e = beg + lane; e < end; e += 64) {
            alpha[e * 2]     *= i0;
            alpha[e * 2 + 1] *= i1;
        }
    }
}

// ---------------- aggregation layer1 (concat): 2 waves split edges, bf16 gather ----------------
// lane covers channels 2*lane, 2*lane+1 (uint = bf16x2); head = lane>>5.
__global__ __launch_bounds__(128) void k_agg1(const int* __restrict__ rowptr, const int* __restrict__ ssrc,
                                              const float* __restrict__ alpha, const unsigned short* __restrict__ hb,
                                              const float* __restrict__ bias, int Nn, float* __restrict__ out) {
    __shared__ float part[128];
    int n = blockIdx.x;
    int t = threadIdx.x, wv = t >> 6, lane = t & 63;
    int head = lane >> 5;
    int beg = rowptr[n], end = rowptr[n + 1];
    float ax = 0.f, ay = 0.f;
    int e = beg + wv;
    for (; e + 6 < end; e += 8) {
        int s0 = ssrc[e], s1 = ssrc[e + 2], s2 = ssrc[e + 4], s3 = ssrc[e + 6];
        float a0 = alpha[(size_t)e * 2 + head];
        float a1 = alpha[(size_t)(e + 2) * 2 + head];
        float a2 = alpha[(size_t)(e + 4) * 2 + head];
        float a3 = alpha[(size_t)(e + 6) * 2 + head];
        float2 v0 = bf2x2(*(const unsigned*)&hb[(size_t)s0 * 128 + lane * 2]);
        float2 v1 = bf2x2(*(const unsigned*)&hb[(size_t)s1 * 128 + lane * 2]);
        float2 v2 = bf2x2(*(const unsigned*)&hb[(size_t)s2 * 128 + lane * 2]);
        float2 v3 = bf2x2(*(const unsigned*)&hb[(size_t)s3 * 128 + lane * 2]);
        ax += a0 * v0.x + a1 * v1.x + a2 * v2.x + a3 * v3.x;
        ay += a0 * v0.y + a1 * v1.y + a2 * v2.y + a3 * v3.y;
    }
    for (; e < end; e += 2) {
        int s = ssrc[e];
        float a = alpha[(size_t)e * 2 + head];
        float2 v = bf2x2(*(const unsigned*)&hb[(size_t)s * 128 + lane * 2]);
        ax += a * v.x; ay += a * v.y;
    }
    if (wv) { part[lane * 2] = ax; part[lane * 2 + 1] = ay; }
    __syncthreads();
    if (!wv) {
        ax += part[lane * 2]; ay += part[lane * 2 + 1];
        float2 bv = *(const float2*)&bias[lane * 2];
        *(float2*)&out[(size_t)n * 128 + lane * 2] = make_float2(ax + bv.x, ay + bv.y);
    }
}

// ---------------- aggregation layer2 (head mean): 2 waves split edges ----------------
// lanes 0..31 head0, 32..63 head1; each lane channels ch, ch+1 of its head.
__global__ __launch_bounds__(128) void k_agg2(const int* __restrict__ rowptr, const int* __restrict__ ssrc,
                                              const float* __restrict__ alpha, const unsigned short* __restrict__ hb,
                                              const float* __restrict__ bias, int Nn, float* __restrict__ out) {
    __shared__ float part[64];
    int n = blockIdx.x;
    int t = threadIdx.x, wv = t >> 6, lane = t & 63;
    int head = lane >> 5;
    int ch = (lane & 31) * 2;
    size_t hoff = (size_t)head * 64 + ch;
    int beg = rowptr[n], end = rowptr[n + 1];
    float ax = 0.f, ay = 0.f;
    int e = beg + wv;
    for (; e + 6 < end; e += 8) {
        int s0 = ssrc[e], s1 = ssrc[e + 2], s2 = ssrc[e + 4], s3 = ssrc[e + 6];
        float a0 = alpha[(size_t)e * 2 + head];
        float a1 = alpha[(size_t)(e + 2) * 2 + head];
        float a2 = alpha[(size_t)(e + 4) * 2 + head];
        float a3 = alpha[(size_t)(e + 6) * 2 + head];
        float2 v0 = bf2x2(*(const unsigned*)&hb[(size_t)s0 * 128 + hoff]);
        float2 v1 = bf2x2(*(const unsigned*)&hb[(size_t)s1 * 128 + hoff]);
        float2 v2 = bf2x2(*(const unsigned*)&hb[(size_t)s2 * 128 + hoff]);
        float2 v3 = bf2x2(*(const unsigned*)&hb[(size_t)s3 * 128 + hoff]);
        ax += a0 * v0.x + a1 * v1.x + a2 * v2.x + a3 * v3.x;
        ay += a0 * v0.y + a1 * v1.y + a2 * v2.y + a3 * v3.y;
    }
    for (; e < end; e += 2) {
        int s = ssrc[e];
        float a = alpha[(size_t)e * 2 + head];
        float2 v = bf2x2(*(const unsigned*)&hb[(size_t)s * 128 + hoff]);
        ax += a * v.x; ay += a * v.y;
    }
    // combine heads: lane j (head0) + lane j+32 (head1)
    ax += __shfl_xor(ax, 32);
    ay += __shfl_xor(ay, 32);
    if (wv && head == 0) { part[ch] = ax; part[ch + 1] = ay; }
    __syncthreads();
    if (!wv && head == 0) {
        ax += part[ch]; ay += part[ch + 1];
        float2 bv = *(const float2*)&bias[ch];
        *(float2*)&out[(size_t)n * 64 + ch] = make_float2(0.5f * ax + bv.x, 0.5f * ay + bv.y);
    }
}

// ---------------- final GEMM [M,64] @ [64,40] + bias, BN affine + ELU fused on A ----------------
__global__ __launch_bounds__(128) void k_gemmf(const float* __restrict__ A, const float* __restrict__ Wf,
                                               const float* __restrict__ bf, const float* __restrict__ st,
                                               int M, float* __restrict__ out) {
    __shared__ float As[128 * 65];
    __shared__ float Bs[64 * 40];
    int t = threadIdx.x;
    int row0 = blockIdx.x * 128;
    for (int i = t; i < 64 * 40; i += 128) Bs[i] = Wf[i];
    for (int i = t; i < 128 * 64; i += 128) {
        int r = i >> 6, k = i & 63;
        int gr = row0 + r;
        float v = 0.f;
        if (gr < M) {
            v = A[(size_t)gr * 64 + k] * st[k] + st[64 + k];
            v = v > 0.f ? v : expm1f(v);
        }
        As[r * 65 + k] = v;
    }
    __syncthreads();
    int cg = t & 3, rg = t >> 2;
    float acc[4][10] = {};
    for (int k = 0; k < 64; k++) {
        float b[10];
        #pragma unroll
        for (int j = 0; j < 10; j++) b[j] = Bs[k * 40 + cg * 10 + j];
        #pragma unroll
        for (int r = 0; r < 4; r++) {
            float a = As[(rg * 4 + r) * 65 + k];
            #pragma unroll
            for (int j = 0; j < 10; j++) acc[r][j] += a * b[j];
        }
    }
    for (int r = 0; r < 4; r++) {
        int gr = row0 + rg * 4 + r;
        if (gr < M) {
            #pragma unroll
            for (int j = 0; j < 10; j++) out[(size_t)gr * 40 + cg * 10 + j] = acc[r][j] + bf[cg * 10 + j];
        }
    }
}

extern "C" void kernel_launch(void* const* d_in, const int* in_sizes, int n_in,
                              void* d_out, int out_size, void* d_ws, size_t ws_size,
                              hipStream_t stream) {
    const float* x     = (const float*)d_in[0];
    const int*   ei    = (const int*)d_in[1];
    const float* bn0_g = (const float*)d_in[2];
    const float* bn0_b = (const float*)d_in[3];
    const float* W1    = (const float*)d_in[4];
    const float* a1s   = (const float*)d_in[5];
    const float* a1d   = (const float*)d_in[6];
    const float* b1    = (const float*)d_in[7];
    const float* bn1_g = (const float*)d_in[8];
    const float* bn1_b = (const float*)d_in[9];
    const float* W2    = (const float*)d_in[10];
    const float* a2s   = (const float*)d_in[11];
    const float* a2d   = (const float*)d_in[12];
    const float* b2    = (const float*)d_in[13];
    const float* bn2_g = (const float*)d_in[14];
    const float* bn2_b = (const float*)d_in[15];
    const float* Wf    = (const float*)d_in[16];
    const float* bf    = (const float*)d_in[17];
    float* out = (float*)d_out;

    const int N  = in_sizes[0] / 128;
    const int E  = in_sizes[1] / 2;
    const int ET = E + N;

    char* ws = (char*)d_ws;
    size_t off = 0;
    auto alloc = [&](size_t bytes) -> char* {
        char* p = ws + off;
        off = (off + bytes + 255) & ~(size_t)255;
        return p;
    };
    int*   cnt    = (int*)alloc((size_t)N * 4);
    int*   rowptr = (int*)alloc((size_t)(N + 1) * 4);
    int*   cursor = (int*)alloc((size_t)N * 4);
    int*   ssrc   = (int*)alloc((size_t)ET * 4);
    float* alpha  = (float*)alloc((size_t)ET * 2 * 4);
    float* hbuf   = (float*)alloc((size_t)N * 128 * 4);
    float* abuf   = (float*)alloc((size_t)N * 128 * 4);
    unsigned short* hb = (unsigned short*)alloc((size_t)N * 128 * 2);
    float* als    = (float*)alloc((size_t)N * 2 * 4);
    float* ald    = (float*)alloc((size_t)N * 2 * 4);
    float* sums   = (float*)alloc(256 * 4);
    float* st     = (float*)alloc(256 * 4);

    const int tb = 256;
    const int egrid = (ET + tb - 1) / tb;
    const int wgrid = (N * 64 + tb - 1) / tb;

    // CSR build (graph identical for both layers)
    hipMemsetAsync(cnt, 0, (size_t)N * 4, stream);
    k_hist<<<egrid, tb, 0, stream>>>(ei, E, N, cnt);
    k_scan<<<1, 1024, 0, stream>>>(cnt, N, rowptr, cursor);
    k_fill<<<egrid, tb, 0, stream>>>(ei, E, N, cursor, ssrc);

    // BN0
    hipMemsetAsync(sums, 0, 256 * 4, stream);
    k_bnstat<<<(N + 63) / 64, 128, 0, stream>>>(x, N, 128, 64, sums);
    k_bnfin<<<1, 128, 0, stream>>>(sums, N, 128, bn0_g, bn0_b, st);

    // layer 1
    dim3 g1((N + 127) / 128, 2);
    k_gemm128<<<g1, 256, 0, stream>>>(x, W1, st, N, 0, hbuf, hb);
    k_al<<<wgrid, tb, 0, stream>>>(hbuf, a1s, a1d, N, als, ald);
    k_attn<<<wgrid, tb, 0, stream>>>(rowptr, ssrc, als, ald, N, alpha);
    k_agg1<<<N, 128, 0, stream>>>(rowptr, ssrc, alpha, hb, b1, N, abuf);

    // BN1
    hipMemsetAsync(sums, 0, 256 * 4, stream);
    k_bnstat<<<(N + 63) / 64, 128, 0, stream>>>(abuf, N, 128, 64, sums);
    k_bnfin<<<1, 128, 0, stream>>>(sums, N, 128, bn1_g, bn1_b, st);

    // layer 2
    k_gemm128<<<g1, 256, 0, stream>>>(abuf, W2, st, N, 1, hbuf, hb);
    k_al<<<wgrid, tb, 0, stream>>>(hbuf, a2s, a2d, N, als, ald);
    k_attn<<<wgrid, tb, 0, stream>>>(rowptr, ssrc, als, ald, N, alpha);
    k_agg2<<<N, 128, 0, stream>>>(rowptr, ssrc, alpha, hb, b2, N, abuf);

    // BN2
    hipMemsetAsync(sums, 0, 256 * 4, stream);
    k_bnstat<<<(N + 63) / 64, 64, 0, stream>>>(abuf, N, 64, 64, sums);
    k_bnfin<<<1, 64, 0, stream>>>(sums, N, 64, bn2_g, bn2_b, st);

    // final linear
    k_gemmf<<<(N + 127) / 128, 128, 0, stream>>>(abuf, Wf, bf, st, N, out);
}

// Round 3
// 527.443 us; speedup vs baseline: 1.4480x; 1.2784x over previous
//
#include <hip/hip_runtime.h>

// GAT 2-layer + BN + final linear on MI355X.
// R3: bf16 MFMA GEMMs (16x16x32) with BN-affine/ELU folded into a bf16 prepass,
// W^T bf16 precompute, attention-logit dot fused into GEMM epilogue (k_al gone),
// GEMM writes only bf16 hb. Aggregation: 16B/lane gathers, 4 edges per wave-iter.

#define NEG_SLOPE 0.2f
#define BN_EPS 1e-5f

typedef short bf16x8 __attribute__((ext_vector_type(8)));
typedef float f32x4 __attribute__((ext_vector_type(4)));

static __device__ __forceinline__ unsigned short f2bf(float f) {
    union { float f; unsigned u; } v; v.f = f;
    unsigned r = v.u + 0x7FFF + ((v.u >> 16) & 1);
    return (unsigned short)(r >> 16);
}
static __device__ __forceinline__ float2 bf2x2(unsigned v) {
    union { unsigned u; float f; } a, b;
    a.u = v << 16; b.u = v & 0xffff0000u;
    return make_float2(a.f, b.f);
}

// ---------------- CSR build ----------------
__global__ void k_hist(const int* __restrict__ ei, int E, int Nn, int* __restrict__ cnt) {
    int i = blockIdx.x * blockDim.x + threadIdx.x;
    if (i >= E + Nn) return;
    int d = (i < E) ? ei[E + i] : (i - E);
    atomicAdd(&cnt[d], 1);
}

__global__ __launch_bounds__(1024) void k_scan(const int* __restrict__ cnt, int Nn,
                                               int* __restrict__ rowptr, int* __restrict__ cursor) {
    __shared__ int wsum[16];
    __shared__ int s_carry, s_tile;
    int t = threadIdx.x, lane = t & 63, w = t >> 6;
    if (t == 0) s_carry = 0;
    __syncthreads();
    for (int base = 0; base < Nn; base += 1024) {
        int i = base + t;
        int v = (i < Nn) ? cnt[i] : 0;
        int x = v;
        #pragma unroll
        for (int off = 1; off < 64; off <<= 1) {
            int y = __shfl_up(x, off);
            if (lane >= off) x += y;
        }
        if (lane == 63) wsum[w] = x;
        __syncthreads();
        int carry = s_carry;
        if (w == 0) {
            int val = (lane < 16) ? wsum[lane] : 0;
            int xs = val;
            #pragma unroll
            for (int off = 1; off < 64; off <<= 1) {
                int y = __shfl_up(xs, off);
                if (lane >= off) xs += y;
            }
            if (lane == 15) s_tile = xs;
            if (lane < 16) wsum[lane] = xs - val;
        }
        __syncthreads();
        if (i < Nn) {
            int pos = carry + wsum[w] + (x - v);
            rowptr[i] = pos;
            cursor[i] = pos;
        }
        __syncthreads();
        if (t == 0) s_carry = carry + s_tile;
        __syncthreads();
    }
    if (threadIdx.x == 0) rowptr[Nn] = s_carry;
}

__global__ void k_fill(const int* __restrict__ ei, int E, int Nn,
                       int* __restrict__ cursor, int* __restrict__ ssrc) {
    int i = blockIdx.x * blockDim.x + threadIdx.x;
    if (i >= E + Nn) return;
    int s, d;
    if (i < E) { s = ei[i]; d = ei[E + i]; }
    else       { s = i - E; d = s; }
    int pos = atomicAdd(&cursor[d], 1);
    ssrc[pos] = s;
}

// ---------------- BatchNorm stats ----------------
__global__ void k_bnstat(const float* __restrict__ x, int M, int C, int rows,
                         float* __restrict__ sums) {
    int c = threadIdx.x;
    int r0 = blockIdx.x * rows;
    int r1 = min(M, r0 + rows);
    float s = 0.f, s2 = 0.f;
    for (int r = r0; r < r1; r++) {
        float v = x[(size_t)r * C + c];
        s += v; s2 += v * v;
    }
    atomicAdd(&sums[c], s);
    atomicAdd(&sums[C + c], s2);
}

__global__ void k_bnfin(const float* __restrict__ sums, int M, int C,
                        const float* __restrict__ g, const float* __restrict__ b,
                        float* __restrict__ st) {
    int c = threadIdx.x;
    if (c < C) {
        float mu = sums[c] / (float)M;
        float var = sums[C + c] / (float)M - mu * mu;
        float s = g[c] * rsqrtf(var + BN_EPS);
        st[c] = s;
        st[C + c] = b[c] - mu * s;
    }
}

// ---------------- prepass: fp32 -> BN affine (+ELU) -> bf16, C=128 ----------------
__global__ __launch_bounds__(256) void k_prep(const float* __restrict__ in, const float* __restrict__ st,
                                              int M, int elu, unsigned short* __restrict__ outb) {
    int tid = blockIdx.x * 256 + threadIdx.x;
    size_t idx = (size_t)tid * 8;
    if (idx >= (size_t)M * 128) return;
    int ch = (int)(idx & 127);
    float4 v0 = *(const float4*)&in[idx];
    float4 v1 = *(const float4*)&in[idx + 4];
    float4 s0 = *(const float4*)&st[ch];
    float4 s1 = *(const float4*)&st[ch + 4];
    float4 t0 = *(const float4*)&st[128 + ch];
    float4 t1 = *(const float4*)&st[128 + ch + 4];
    float a[8] = {v0.x*s0.x+t0.x, v0.y*s0.y+t0.y, v0.z*s0.z+t0.z, v0.w*s0.w+t0.w,
                  v1.x*s1.x+t1.x, v1.y*s1.y+t1.y, v1.z*s1.z+t1.z, v1.w*s1.w+t1.w};
    if (elu) {
        #pragma unroll
        for (int j = 0; j < 8; j++) a[j] = a[j] > 0.f ? a[j] : expm1f(a[j]);
    }
    uint4 p;
    p.x = ((unsigned)f2bf(a[1]) << 16) | f2bf(a[0]);
    p.y = ((unsigned)f2bf(a[3]) << 16) | f2bf(a[2]);
    p.z = ((unsigned)f2bf(a[5]) << 16) | f2bf(a[4]);
    p.w = ((unsigned)f2bf(a[7]) << 16) | f2bf(a[6]);
    *(uint4*)&outb[idx] = p;
}

// ---------------- W^T bf16: wt[n][k] = W[k][n], 128x128 ----------------
__global__ __launch_bounds__(256) void k_wt(const float* __restrict__ W, unsigned short* __restrict__ wt) {
    int idx = blockIdx.x * 256 + threadIdx.x;
    if (idx >= 128 * 128) return;
    int n = idx >> 7, k = idx & 127;
    wt[idx] = f2bf(W[k * 128 + n]);
}

// ---------------- MFMA GEMM [M,128]@[128,128] -> bf16 hb; epilogue: als/ald dot ----------------
// BM=64, 256 threads (4 waves x 16 rows x 128 cols), 16x16x32 bf16 MFMA.
// LDS rows padded to 136 bf16 (272B): conflict-free b128 frag reads.
__global__ __launch_bounds__(256) void k_mfma(
    const unsigned short* __restrict__ abf, const unsigned short* __restrict__ wt,
    const float* __restrict__ asrc, const float* __restrict__ adst, int M,
    unsigned short* __restrict__ hb, float* __restrict__ als, float* __restrict__ ald) {
    __shared__ unsigned short As[64 * 136];
    __shared__ unsigned short Bs[128 * 136];
    const int t = threadIdx.x;
    const int w = t >> 6, lane = t & 63;
    const int c = lane & 15, q = lane >> 4;
    const int row0 = blockIdx.x * 64;

    #pragma unroll
    for (int i = 0; i < 4; i++) {                 // A tile: 64 rows x 128k
        int idx = t + i * 256;
        int r = idx >> 4, ch = idx & 15;
        uint4 v = make_uint4(0, 0, 0, 0);
        if (row0 + r < M) v = *(const uint4*)&abf[(size_t)(row0 + r) * 128 + ch * 8];
        *(uint4*)&As[r * 136 + ch * 8] = v;
    }
    #pragma unroll
    for (int i = 0; i < 8; i++) {                 // B tile: 128 n x 128 k (W^T)
        int idx = t + i * 256;
        int r = idx >> 4, ch = idx & 15;
        *(uint4*)&Bs[r * 136 + ch * 8] = *(const uint4*)&wt[(size_t)r * 128 + ch * 8];
    }
    __syncthreads();

    f32x4 acc[8] = {};
    #pragma unroll
    for (int ks = 0; ks < 4; ks++) {
        bf16x8 a = *(bf16x8*)&As[(w * 16 + c) * 136 + (ks * 4 + q) * 8];
        #pragma unroll
        for (int tl = 0; tl < 8; tl++) {
            bf16x8 b = *(bf16x8*)&Bs[(tl * 16 + c) * 136 + (ks * 4 + q) * 8];
            acc[tl] = __builtin_amdgcn_mfma_f32_16x16x32_bf16(a, b, acc[tl], 0, 0, 0);
        }
    }

    // epilogue 1: bf16 h store. C/D: col = c, row = q*4 + reg.
    #pragma unroll
    for (int reg = 0; reg < 4; reg++) {
        int grow = row0 + w * 16 + q * 4 + reg;
        if (grow < M) {
            #pragma unroll
            for (int tl = 0; tl < 8; tl++)
                hb[(size_t)grow * 128 + tl * 16 + c] = f2bf(acc[tl][reg]);
        }
    }

    // epilogue 2: attention logits als/ald (dot over channels, reduce over 16 cols)
    float as_[8], ad_[8];
    #pragma unroll
    for (int tl = 0; tl < 8; tl++) { as_[tl] = asrc[tl * 16 + c]; ad_[tl] = adst[tl * 16 + c]; }
    #pragma unroll
    for (int reg = 0; reg < 4; reg++) {
        float s0 = 0.f, s1 = 0.f, d0 = 0.f, d1 = 0.f;
        #pragma unroll
        for (int tl = 0; tl < 4; tl++) { s0 += acc[tl][reg] * as_[tl]; d0 += acc[tl][reg] * ad_[tl]; }
        #pragma unroll
        for (int tl = 4; tl < 8; tl++) { s1 += acc[tl][reg] * as_[tl]; d1 += acc[tl][reg] * ad_[tl]; }
        #pragma unroll
        for (int off = 1; off < 16; off <<= 1) {
            s0 += __shfl_xor(s0, off); s1 += __shfl_xor(s1, off);
            d0 += __shfl_xor(d0, off); d1 += __shfl_xor(d1, off);
        }
        int grow = row0 + w * 16 + q * 4 + reg;
        if (c == 0 && grow < M) {
            *(float2*)&als[(size_t)grow * 2] = make_float2(s0, s1);
            *(float2*)&ald[(size_t)grow * 2] = make_float2(d0, d1);
        }
    }
}

// ---------------- segment softmax: wave per dst node ----------------
__global__ void k_attn(const int* __restrict__ rowptr, const int* __restrict__ ssrc,
                       const float* __restrict__ als, const float* __restrict__ ald,
                       int Nn, float* __restrict__ alpha) {
    int g = blockIdx.x * blockDim.x + threadIdx.x;
    int w = g >> 6, lane = g & 63;
    if (w >= Nn) return;
    int beg = rowptr[w], end = rowptr[w + 1];
    int deg = end - beg;
    float2 dv = *(const float2*)&ald[(size_t)w * 2];
    if (deg <= 64) {
        bool on = lane < deg;
        int e = beg + (on ? lane : 0);
        int s = ssrc[e];
        float2 av = *(const float2*)&als[(size_t)s * 2];
        float v0 = av.x + dv.x; v0 = v0 > 0.f ? v0 : NEG_SLOPE * v0;
        float v1 = av.y + dv.y; v1 = v1 > 0.f ? v1 : NEG_SLOPE * v1;
        float m0 = on ? v0 : -1e30f, m1 = on ? v1 : -1e30f;
        #pragma unroll
        for (int off = 32; off; off >>= 1) {
            m0 = fmaxf(m0, __shfl_xor(m0, off));
            m1 = fmaxf(m1, __shfl_xor(m1, off));
        }
        float p0 = on ? __expf(v0 - m0) : 0.f;
        float p1 = on ? __expf(v1 - m1) : 0.f;
        float t0 = p0, t1 = p1;
        #pragma unroll
        for (int off = 32; off; off >>= 1) {
            t0 += __shfl_xor(t0, off);
            t1 += __shfl_xor(t1, off);
        }
        if (on) *(float2*)&alpha[(size_t)e * 2] = make_float2(p0 / t0, p1 / t1);
    } else {
        float d0 = dv.x, d1 = dv.y;
        float m0 = -1e30f, m1 = -1e30f;
        for (int e = beg + lane; e < end; e += 64) {
            int s = ssrc[e];
            float v0 = als[s * 2] + d0;     v0 = v0 > 0.f ? v0 : NEG_SLOPE * v0;
            float v1 = als[s * 2 + 1] + d1; v1 = v1 > 0.f ? v1 : NEG_SLOPE * v1;
            m0 = fmaxf(m0, v0); m1 = fmaxf(m1, v1);
        }
        #pragma unroll
        for (int off = 32; off; off >>= 1) {
            m0 = fmaxf(m0, __shfl_xor(m0, off));
            m1 = fmaxf(m1, __shfl_xor(m1, off));
        }
        float t0 = 0.f, t1 = 0.f;
        for (int e = beg + lane; e < end; e += 64) {
            int s = ssrc[e];
            float v0 = als[s * 2] + d0;     v0 = v0 > 0.f ? v0 : NEG_SLOPE * v0;
            float v1 = als[s * 2 + 1] + d1; v1 = v1 > 0.f ? v1 : NEG_SLOPE * v1;
            float p0 = __expf(v0 - m0), p1 = __expf(v1 - m1);
            alpha[e * 2] = p0; alpha[e * 2 + 1] = p1;
            t0 += p0; t1 += p1;
        }
        #pragma unroll
        for (int off = 32; off; off >>= 1) {
            t0 += __shfl_xor(t0, off);
            t1 += __shfl_xor(t1, off);
        }
        float i0 = 1.f / t0, i1 = 1.f / t1;
        for (int e = beg + lane; e < end; e += 64) {
            alpha[e * 2]     *= i0;
            alpha[e * 2 + 1] *= i1;
        }
    }
}

// ---------------- aggregation: wave per node, 16B/lane gathers, 4 edges/iter ----------------
// lane: sub = lane>>4 (edge slot), c = lane&15 (channel chunk of 8), head = c>>3.
static __device__ __forceinline__ void acc8(float* acc, uint4 v, float a) {
    float2 p;
    p = bf2x2(v.x); acc[0] += a * p.x; acc[1] += a * p.y;
    p = bf2x2(v.y); acc[2] += a * p.x; acc[3] += a * p.y;
    p = bf2x2(v.z); acc[4] += a * p.x; acc[5] += a * p.y;
    p = bf2x2(v.w); acc[6] += a * p.x; acc[7] += a * p.y;
}

__global__ __launch_bounds__(256) void k_agg1(const int* __restrict__ rowptr, const int* __restrict__ ssrc,
                                              const float* __restrict__ alpha, const unsigned short* __restrict__ hb,
                                              const float* __restrict__ bias, int Nn, float* __restrict__ out) {
    int gw = (blockIdx.x * blockDim.x + threadIdx.x) >> 6;
    if (gw >= Nn) return;
    int lane = threadIdx.x & 63;
    int sub = lane >> 4, c = lane & 15, head = c >> 3;
    int beg = rowptr[gw], end = rowptr[gw + 1];
    float acc[8] = {};
    int e = beg + sub;
    for (; e + 4 < end; e += 8) {
        int s0 = ssrc[e], s1 = ssrc[e + 4];
        float a0 = alpha[(size_t)e * 2 + head];
        float a1 = alpha[(size_t)(e + 4) * 2 + head];
        uint4 v0 = *(const uint4*)&hb[(size_t)s0 * 128 + c * 8];
        uint4 v1 = *(const uint4*)&hb[(size_t)s1 * 128 + c * 8];
        acc8(acc, v0, a0); acc8(acc, v1, a1);
    }
    for (; e < end; e += 4) {
        int s = ssrc[e];
        float a = alpha[(size_t)e * 2 + head];
        uint4 v = *(const uint4*)&hb[(size_t)s * 128 + c * 8];
        acc8(acc, v, a);
    }
    #pragma unroll
    for (int j = 0; j < 8; j++) {
        acc[j] += __shfl_xor(acc[j], 16);
        acc[j] += __shfl_xor(acc[j], 32);
    }
    if (sub == 0) {
        float4 b0 = *(const float4*)&bias[c * 8];
        float4 b1 = *(const float4*)&bias[c * 8 + 4];
        float4 o0 = make_float4(acc[0] + b0.x, acc[1] + b0.y, acc[2] + b0.z, acc[3] + b0.w);
        float4 o1 = make_float4(acc[4] + b1.x, acc[5] + b1.y, acc[6] + b1.z, acc[7] + b1.w);
        *(float4*)&out[(size_t)gw * 128 + c * 8] = o0;
        *(float4*)&out[(size_t)gw * 128 + c * 8 + 4] = o1;
    }
}

__global__ __launch_bounds__(256) void k_agg2(const int* __restrict__ rowptr, const int* __restrict__ ssrc,
                                              const float* __restrict__ alpha, const unsigned short* __restrict__ hb,
                                              const float* __restrict__ bias, int Nn, float* __restrict__ out) {
    int gw = (blockIdx.x * blockDim.x + threadIdx.x) >> 6;
    if (gw >= Nn) return;
    int lane = threadIdx.x & 63;
    int sub = lane >> 4, c = lane & 15, head = c >> 3;
    int beg = rowptr[gw], end = rowptr[gw + 1];
    float acc[8] = {};
    int e = beg + sub;
    for (; e + 4 < end; e += 8) {
        int s0 = ssrc[e], s1 = ssrc[e + 4];
        float a0 = alpha[(size_t)e * 2 + head];
        float a1 = alpha[(size_t)(e + 4) * 2 + head];
        uint4 v0 = *(const uint4*)&hb[(size_t)s0 * 128 + c * 8];
        uint4 v1 = *(const uint4*)&hb[(size_t)s1 * 128 + c * 8];
        acc8(acc, v0, a0); acc8(acc, v1, a1);
    }
    for (; e < end; e += 4) {
        int s = ssrc[e];
        float a = alpha[(size_t)e * 2 + head];
        uint4 v = *(const uint4*)&hb[(size_t)s * 128 + c * 8];
        acc8(acc, v, a);
    }
    #pragma unroll
    for (int j = 0; j < 8; j++) {
        acc[j] += __shfl_xor(acc[j], 16);
        acc[j] += __shfl_xor(acc[j], 32);
        acc[j] += __shfl_xor(acc[j], 8);   // combine heads (c ^ 8 <=> ch ^ 64)
    }
    if (sub == 0 && c < 8) {
        float4 b0 = *(const float4*)&bias[c * 8];
        float4 b1 = *(const float4*)&bias[c * 8 + 4];
        float4 o0 = make_float4(0.5f * acc[0] + b0.x, 0.5f * acc[1] + b0.y, 0.5f * acc[2] + b0.z, 0.5f * acc[3] + b0.w);
        float4 o1 = make_float4(0.5f * acc[4] + b1.x, 0.5f * acc[5] + b1.y, 0.5f * acc[6] + b1.z, 0.5f * acc[7] + b1.w);
        *(float4*)&out[(size_t)gw * 64 + c * 8] = o0;
        *(float4*)&out[(size_t)gw * 64 + c * 8 + 4] = o1;
    }
}

// ---------------- final GEMM [M,64] @ [64,40] + bias, BN affine + ELU fused on A ----------------
__global__ __launch_bounds__(128) void k_gemmf(const float* __restrict__ A, const float* __restrict__ Wf,
                                               const float* __restrict__ bf, const float* __restrict__ st,
                                               int M, float* __restrict__ out) {
    __shared__ float As[128 * 65];
    __shared__ float Bs[64 * 40];
    int t = threadIdx.x;
    int row0 = blockIdx.x * 128;
    for (int i = t; i < 64 * 40; i += 128) Bs[i] = Wf[i];
    for (int i = t; i < 128 * 64; i += 128) {
        int r = i >> 6, k = i & 63;
        int gr = row0 + r;
        float v = 0.f;
        if (gr < M) {
            v = A[(size_t)gr * 64 + k] * st[k] + st[64 + k];
            v = v > 0.f ? v : expm1f(v);
        }
        As[r * 65 + k] = v;
    }
    __syncthreads();
    int cg = t & 3, rg = t >> 2;
    float acc[4][10] = {};
    for (int k = 0; k < 64; k++) {
        float b[10];
        #pragma unroll
        for (int j = 0; j < 10; j++) b[j] = Bs[k * 40 + cg * 10 + j];
        #pragma unroll
        for (int r = 0; r < 4; r++) {
            float a = As[(rg * 4 + r) * 65 + k];
            #pragma unroll
            for (int j = 0; j < 10; j++) acc[r][j] += a * b[j];
        }
    }
    for (int r = 0; r < 4; r++) {
        int gr = row0 + rg * 4 + r;
        if (gr < M) {
            #pragma unroll
            for (int j = 0; j < 10; j++) out[(size_t)gr * 40 + cg * 10 + j] = acc[r][j] + bf[cg * 10 + j];
        }
    }
}

extern "C" void kernel_launch(void* const* d_in, const int* in_sizes, int n_in,
                              void* d_out, int out_size, void* d_ws, size_t ws_size,
                              hipStream_t stream) {
    const float* x     = (const float*)d_in[0];
    const int*   ei    = (const int*)d_in[1];
    const float* bn0_g = (const float*)d_in[2];
    const float* bn0_b = (const float*)d_in[3];
    const float* W1    = (const float*)d_in[4];
    const float* a1s   = (const float*)d_in[5];
    const float* a1d   = (const float*)d_in[6];
    const float* b1    = (const float*)d_in[7];
    const float* bn1_g = (const float*)d_in[8];
    const float* bn1_b = (const float*)d_in[9];
    const float* W2    = (const float*)d_in[10];
    const float* a2s   = (const float*)d_in[11];
    const float* a2d   = (const float*)d_in[12];
    const float* b2    = (const float*)d_in[13];
    const float* bn2_g = (const float*)d_in[14];
    const float* bn2_b = (const float*)d_in[15];
    const float* Wf    = (const float*)d_in[16];
    const float* bf    = (const float*)d_in[17];
    float* out = (float*)d_out;

    const int N  = in_sizes[0] / 128;
    const int E  = in_sizes[1] / 2;
    const int ET = E + N;

    char* ws = (char*)d_ws;
    size_t off = 0;
    auto alloc = [&](size_t bytes) -> char* {
        char* p = ws + off;
        off = (off + bytes + 255) & ~(size_t)255;
        return p;
    };
    int*   cnt    = (int*)alloc((size_t)N * 4);
    int*   rowptr = (int*)alloc((size_t)(N + 1) * 4);
    int*   cursor = (int*)alloc((size_t)N * 4);
    int*   ssrc   = (int*)alloc((size_t)ET * 4);
    float* alpha  = (float*)alloc((size_t)ET * 2 * 4);
    float* abuf   = (float*)alloc((size_t)N * 128 * 4);
    unsigned short* abf = (unsigned short*)alloc((size_t)N * 128 * 2);
    unsigned short* hb  = (unsigned short*)alloc((size_t)N * 128 * 2);
    unsigned short* wt  = (unsigned short*)alloc((size_t)128 * 128 * 2);
    float* als    = (float*)alloc((size_t)N * 2 * 4);
    float* ald    = (float*)alloc((size_t)N * 2 * 4);
    float* sums   = (float*)alloc(256 * 4);
    float* st     = (float*)alloc(256 * 4);

    const int tb = 256;
    const int egrid = (ET + tb - 1) / tb;
    const int wgrid = ((size_t)N * 64 + tb - 1) / tb;   // wave-per-node kernels
    const int pgrid = ((size_t)N * 16 + tb - 1) / tb;   // prepass (8 elems/thread)
    const int ggrid = (N + 63) / 64;                    // mfma gemm blocks

    // CSR build (graph identical for both layers)
    hipMemsetAsync(cnt, 0, (size_t)N * 4, stream);
    k_hist<<<egrid, tb, 0, stream>>>(ei, E, N, cnt);
    k_scan<<<1, 1024, 0, stream>>>(cnt, N, rowptr, cursor);
    k_fill<<<egrid, tb, 0, stream>>>(ei, E, N, cursor, ssrc);

    // BN0
    hipMemsetAsync(sums, 0, 256 * 4, stream);
    k_bnstat<<<(N + 63) / 64, 128, 0, stream>>>(x, N, 128, 64, sums);
    k_bnfin<<<1, 128, 0, stream>>>(sums, N, 128, bn0_g, bn0_b, st);

    // layer 1
    k_prep<<<pgrid, tb, 0, stream>>>(x, st, N, 0, abf);
    k_wt<<<64, tb, 0, stream>>>(W1, wt);
    k_mfma<<<ggrid, tb, 0, stream>>>(abf, wt, a1s, a1d, N, hb, als, ald);
    k_attn<<<wgrid, tb, 0, stream>>>(rowptr, ssrc, als, ald, N, alpha);
    k_agg1<<<wgrid, tb, 0, stream>>>(rowptr, ssrc, alpha, hb, b1, N, abuf);

    // BN1
    hipMemsetAsync(sums, 0, 256 * 4, stream);
    k_bnstat<<<(N + 63) / 64, 128, 0, stream>>>(abuf, N, 128, 64, sums);
    k_bnfin<<<1, 128, 0, stream>>>(sums, N, 128, bn1_g, bn1_b, st);

    // layer 2
    k_prep<<<pgrid, tb, 0, stream>>>(abuf, st, N, 1, abf);
    k_wt<<<64, tb, 0, stream>>>(W2, wt);
    k_mfma<<<ggrid, tb, 0, stream>>>(abf, wt, a2s, a2d, N, hb, als, ald);
    k_attn<<<wgrid, tb, 0, stream>>>(rowptr, ssrc, als, ald, N, alpha);
    k_agg2<<<wgrid, tb, 0, stream>>>(rowptr, ssrc, alpha, hb, b2, N, abuf);

    // BN2
    hipMemsetAsync(sums, 0, 256 * 4, stream);
    k_bnstat<<<(N + 63) / 64, 64, 0, stream>>>(abuf, N, 64, 64, sums);
    k_bnfin<<<1, 64, 0, stream>>>(sums, N, 64, bn2_g, bn2_b, st);

    // final linear
    k_gemmf<<<(N + 127) / 128, 128, 0, stream>>>(abuf, Wf, bf, st, N, out);
}

// Round 4
// 474.076 us; speedup vs baseline: 1.6110x; 1.1126x over previous
//
#include <hip/hip_runtime.h>

// GAT 2-layer + BN + final linear on MI355X.
// R4: multi-block 3-phase scan (k_part / k_scanp / k_scan2) replaces the
// single-workgroup k_scan (was 53 us serial, 0.16% occupancy).

#define NEG_SLOPE 0.2f
#define BN_EPS 1e-5f

typedef short bf16x8 __attribute__((ext_vector_type(8)));
typedef float f32x4 __attribute__((ext_vector_type(4)));

static __device__ __forceinline__ unsigned short f2bf(float f) {
    union { float f; unsigned u; } v; v.f = f;
    unsigned r = v.u + 0x7FFF + ((v.u >> 16) & 1);
    return (unsigned short)(r >> 16);
}
static __device__ __forceinline__ float2 bf2x2(unsigned v) {
    union { unsigned u; float f; } a, b;
    a.u = v << 16; b.u = v & 0xffff0000u;
    return make_float2(a.f, b.f);
}

// ---------------- CSR build ----------------
__global__ void k_hist(const int* __restrict__ ei, int E, int Nn, int* __restrict__ cnt) {
    int i = blockIdx.x * blockDim.x + threadIdx.x;
    if (i >= E + Nn) return;
    int d = (i < E) ? ei[E + i] : (i - E);
    atomicAdd(&cnt[d], 1);
}

// phase 1: per-block (1024-tile) reduction
__global__ __launch_bounds__(1024) void k_part(const int* __restrict__ cnt, int Nn,
                                               int* __restrict__ part) {
    __shared__ int ws[16];
    int t = threadIdx.x, lane = t & 63, w = t >> 6;
    int i = blockIdx.x * 1024 + t;
    int v = (i < Nn) ? cnt[i] : 0;
    #pragma unroll
    for (int off = 32; off; off >>= 1) v += __shfl_xor(v, off);
    if (lane == 0) ws[w] = v;
    __syncthreads();
    if (t < 16) {
        int s = ws[t];
        #pragma unroll
        for (int off = 8; off; off >>= 1) s += __shfl_xor(s, off);
        if (t == 0) part[blockIdx.x] = s;
    }
}

// phase 2: single-wave exclusive scan of partials; writes total to rowptr[Nn]
__global__ __launch_bounds__(64) void k_scanp(int* __restrict__ part, int nb,
                                              int Nn, int* __restrict__ rowptr) {
    int lane = threadIdx.x;
    int carry = 0;
    for (int base = 0; base < nb; base += 64) {
        int i = base + lane;
        int v = (i < nb) ? part[i] : 0;
        int x = v;
        #pragma unroll
        for (int off = 1; off < 64; off <<= 1) {
            int y = __shfl_up(x, off);
            if (lane >= off) x += y;
        }
        if (i < nb) part[i] = carry + x - v;     // exclusive
        carry += __shfl(x, 63);
    }
    if (lane == 0) rowptr[Nn] = carry;
}

// phase 3: block-local scan + block offset
__global__ __launch_bounds__(1024) void k_scan2(const int* __restrict__ cnt, int Nn,
                                                const int* __restrict__ part,
                                                int* __restrict__ rowptr, int* __restrict__ cursor) {
    __shared__ int wsum[16];
    int t = threadIdx.x, lane = t & 63, w = t >> 6;
    int i = blockIdx.x * 1024 + t;
    int v = (i < Nn) ? cnt[i] : 0;
    int x = v;
    #pragma unroll
    for (int off = 1; off < 64; off <<= 1) {
        int y = __shfl_up(x, off);
        if (lane >= off) x += y;
    }
    if (lane == 63) wsum[w] = x;
    __syncthreads();
    if (w == 0) {
        int val = (lane < 16) ? wsum[lane] : 0;
        int xs = val;
        #pragma unroll
        for (int off = 1; off < 16; off <<= 1) {
            int y = __shfl_up(xs, off);
            if (lane >= off) xs += y;
        }
        if (lane < 16) wsum[lane] = xs - val;    // exclusive wave offsets
    }
    __syncthreads();
    if (i < Nn) {
        int pos = part[blockIdx.x] + wsum[w] + (x - v);
        rowptr[i] = pos;
        cursor[i] = pos;
    }
}

__global__ void k_fill(const int* __restrict__ ei, int E, int Nn,
                       int* __restrict__ cursor, int* __restrict__ ssrc) {
    int i = blockIdx.x * blockDim.x + threadIdx.x;
    if (i >= E + Nn) return;
    int s, d;
    if (i < E) { s = ei[i]; d = ei[E + i]; }
    else       { s = i - E; d = s; }
    int pos = atomicAdd(&cursor[d], 1);
    ssrc[pos] = s;
}

// ---------------- BatchNorm stats ----------------
__global__ void k_bnstat(const float* __restrict__ x, int M, int C, int rows,
                         float* __restrict__ sums) {
    int c = threadIdx.x;
    int r0 = blockIdx.x * rows;
    int r1 = min(M, r0 + rows);
    float s = 0.f, s2 = 0.f;
    for (int r = r0; r < r1; r++) {
        float v = x[(size_t)r * C + c];
        s += v; s2 += v * v;
    }
    atomicAdd(&sums[c], s);
    atomicAdd(&sums[C + c], s2);
}

__global__ void k_bnfin(const float* __restrict__ sums, int M, int C,
                        const float* __restrict__ g, const float* __restrict__ b,
                        float* __restrict__ st) {
    int c = threadIdx.x;
    if (c < C) {
        float mu = sums[c] / (float)M;
        float var = sums[C + c] / (float)M - mu * mu;
        float s = g[c] * rsqrtf(var + BN_EPS);
        st[c] = s;
        st[C + c] = b[c] - mu * s;
    }
}

// ---------------- prepass: fp32 -> BN affine (+ELU) -> bf16, C=128 ----------------
__global__ __launch_bounds__(256) void k_prep(const float* __restrict__ in, const float* __restrict__ st,
                                              int M, int elu, unsigned short* __restrict__ outb) {
    int tid = blockIdx.x * 256 + threadIdx.x;
    size_t idx = (size_t)tid * 8;
    if (idx >= (size_t)M * 128) return;
    int ch = (int)(idx & 127);
    float4 v0 = *(const float4*)&in[idx];
    float4 v1 = *(const float4*)&in[idx + 4];
    float4 s0 = *(const float4*)&st[ch];
    float4 s1 = *(const float4*)&st[ch + 4];
    float4 t0 = *(const float4*)&st[128 + ch];
    float4 t1 = *(const float4*)&st[128 + ch + 4];
    float a[8] = {v0.x*s0.x+t0.x, v0.y*s0.y+t0.y, v0.z*s0.z+t0.z, v0.w*s0.w+t0.w,
                  v1.x*s1.x+t1.x, v1.y*s1.y+t1.y, v1.z*s1.z+t1.z, v1.w*s1.w+t1.w};
    if (elu) {
        #pragma unroll
        for (int j = 0; j < 8; j++) a[j] = a[j] > 0.f ? a[j] : expm1f(a[j]);
    }
    uint4 p;
    p.x = ((unsigned)f2bf(a[1]) << 16) | f2bf(a[0]);
    p.y = ((unsigned)f2bf(a[3]) << 16) | f2bf(a[2]);
    p.z = ((unsigned)f2bf(a[5]) << 16) | f2bf(a[4]);
    p.w = ((unsigned)f2bf(a[7]) << 16) | f2bf(a[6]);
    *(uint4*)&outb[idx] = p;
}

// ---------------- W^T bf16: wt[n][k] = W[k][n], 128x128 ----------------
__global__ __launch_bounds__(256) void k_wt(const float* __restrict__ W, unsigned short* __restrict__ wt) {
    int idx = blockIdx.x * 256 + threadIdx.x;
    if (idx >= 128 * 128) return;
    int n = idx >> 7, k = idx & 127;
    wt[idx] = f2bf(W[k * 128 + n]);
}

// ---------------- MFMA GEMM [M,128]@[128,128] -> bf16 hb; epilogue: als/ald dot ----------------
__global__ __launch_bounds__(256) void k_mfma(
    const unsigned short* __restrict__ abf, const unsigned short* __restrict__ wt,
    const float* __restrict__ asrc, const float* __restrict__ adst, int M,
    unsigned short* __restrict__ hb, float* __restrict__ als, float* __restrict__ ald) {
    __shared__ unsigned short As[64 * 136];
    __shared__ unsigned short Bs[128 * 136];
    const int t = threadIdx.x;
    const int w = t >> 6, lane = t & 63;
    const int c = lane & 15, q = lane >> 4;
    const int row0 = blockIdx.x * 64;

    #pragma unroll
    for (int i = 0; i < 4; i++) {                 // A tile: 64 rows x 128k
        int idx = t + i * 256;
        int r = idx >> 4, ch = idx & 15;
        uint4 v = make_uint4(0, 0, 0, 0);
        if (row0 + r < M) v = *(const uint4*)&abf[(size_t)(row0 + r) * 128 + ch * 8];
        *(uint4*)&As[r * 136 + ch * 8] = v;
    }
    #pragma unroll
    for (int i = 0; i < 8; i++) {                 // B tile: 128 n x 128 k (W^T)
        int idx = t + i * 256;
        int r = idx >> 4, ch = idx & 15;
        *(uint4*)&Bs[r * 136 + ch * 8] = *(const uint4*)&wt[(size_t)r * 128 + ch * 8];
    }
    __syncthreads();

    f32x4 acc[8] = {};
    #pragma unroll
    for (int ks = 0; ks < 4; ks++) {
        bf16x8 a = *(bf16x8*)&As[(w * 16 + c) * 136 + (ks * 4 + q) * 8];
        #pragma unroll
        for (int tl = 0; tl < 8; tl++) {
            bf16x8 b = *(bf16x8*)&Bs[(tl * 16 + c) * 136 + (ks * 4 + q) * 8];
            acc[tl] = __builtin_amdgcn_mfma_f32_16x16x32_bf16(a, b, acc[tl], 0, 0, 0);
        }
    }

    // epilogue 1: bf16 h store. C/D: col = c, row = q*4 + reg.
    #pragma unroll
    for (int reg = 0; reg < 4; reg++) {
        int grow = row0 + w * 16 + q * 4 + reg;
        if (grow < M) {
            #pragma unroll
            for (int tl = 0; tl < 8; tl++)
                hb[(size_t)grow * 128 + tl * 16 + c] = f2bf(acc[tl][reg]);
        }
    }

    // epilogue 2: attention logits als/ald
    float as_[8], ad_[8];
    #pragma unroll
    for (int tl = 0; tl < 8; tl++) { as_[tl] = asrc[tl * 16 + c]; ad_[tl] = adst[tl * 16 + c]; }
    #pragma unroll
    for (int reg = 0; reg < 4; reg++) {
        float s0 = 0.f, s1 = 0.f, d0 = 0.f, d1 = 0.f;
        #pragma unroll
        for (int tl = 0; tl < 4; tl++) { s0 += acc[tl][reg] * as_[tl]; d0 += acc[tl][reg] * ad_[tl]; }
        #pragma unroll
        for (int tl = 4; tl < 8; tl++) { s1 += acc[tl][reg] * as_[tl]; d1 += acc[tl][reg] * ad_[tl]; }
        #pragma unroll
        for (int off = 1; off < 16; off <<= 1) {
            s0 += __shfl_xor(s0, off); s1 += __shfl_xor(s1, off);
            d0 += __shfl_xor(d0, off); d1 += __shfl_xor(d1, off);
        }
        int grow = row0 + w * 16 + q * 4 + reg;
        if (c == 0 && grow < M) {
            *(float2*)&als[(size_t)grow * 2] = make_float2(s0, s1);
            *(float2*)&ald[(size_t)grow * 2] = make_float2(d0, d1);
        }
    }
}

// ---------------- segment softmax: wave per dst node ----------------
__global__ void k_attn(const int* __restrict__ rowptr, const int* __restrict__ ssrc,
                       const float* __restrict__ als, const float* __restrict__ ald,
                       int Nn, float* __restrict__ alpha) {
    int g = blockIdx.x * blockDim.x + threadIdx.x;
    int w = g >> 6, lane = g & 63;
    if (w >= Nn) return;
    int beg = rowptr[w], end = rowptr[w + 1];
    int deg = end - beg;
    float2 dv = *(const float2*)&ald[(size_t)w * 2];
    if (deg <= 64) {
        bool on = lane < deg;
        int e = beg + (on ? lane : 0);
        int s = ssrc[e];
        float2 av = *(const float2*)&als[(size_t)s * 2];
        float v0 = av.x + dv.x; v0 = v0 > 0.f ? v0 : NEG_SLOPE * v0;
        float v1 = av.y + dv.y; v1 = v1 > 0.f ? v1 : NEG_SLOPE * v1;
        float m0 = on ? v0 : -1e30f, m1 = on ? v1 : -1e30f;
        #pragma unroll
        for (int off = 32; off; off >>= 1) {
            m0 = fmaxf(m0, __shfl_xor(m0, off));
            m1 = fmaxf(m1, __shfl_xor(m1, off));
        }
        float p0 = on ? __expf(v0 - m0) : 0.f;
        float p1 = on ? __expf(v1 - m1) : 0.f;
        float t0 = p0, t1 = p1;
        #pragma unroll
        for (int off = 32; off; off >>= 1) {
            t0 += __shfl_xor(t0, off);
            t1 += __shfl_xor(t1, off);
        }
        if (on) *(float2*)&alpha[(size_t)e * 2] = make_float2(p0 / t0, p1 / t1);
    } else {
        float d0 = dv.x, d1 = dv.y;
        float m0 = -1e30f, m1 = -1e30f;
        for (int e = beg + lane; e < end; e += 64) {
            int s = ssrc[e];
            float v0 = als[s * 2] + d0;     v0 = v0 > 0.f ? v0 : NEG_SLOPE * v0;
            float v1 = als[s * 2 + 1] + d1; v1 = v1 > 0.f ? v1 : NEG_SLOPE * v1;
            m0 = fmaxf(m0, v0); m1 = fmaxf(m1, v1);
        }
        #pragma unroll
        for (int off = 32; off; off >>= 1) {
            m0 = fmaxf(m0, __shfl_xor(m0, off));
            m1 = fmaxf(m1, __shfl_xor(m1, off));
        }
        float t0 = 0.f, t1 = 0.f;
        for (int e = beg + lane; e < end; e += 64) {
            int s = ssrc[e];
            float v0 = als[s * 2] + d0;     v0 = v0 > 0.f ? v0 : NEG_SLOPE * v0;
            float v1 = als[s * 2 + 1] + d1; v1 = v1 > 0.f ? v1 : NEG_SLOPE * v1;
            float p0 = __expf(v0 - m0), p1 = __expf(v1 - m1);
            alpha[e * 2] = p0; alpha[e * 2 + 1] = p1;
            t0 += p0; t1 += p1;
        }
        #pragma unroll
        for (int off = 32; off; off >>= 1) {
            t0 += __shfl_xor(t0, off);
            t1 += __shfl_xor(t1, off);
        }
        float i0 = 1.f / t0, i1 = 1.f / t1;
        for (int e = beg + lane; e < end; e += 64) {
            alpha[e * 2]     *= i0;
            alpha[e * 2 + 1] *= i1;
        }
    }
}

// ---------------- aggregation: wave per node, 16B/lane gathers, 4 edges/iter ----------------
static __device__ __forceinline__ void acc8(float* acc, uint4 v, float a) {
    float2 p;
    p = bf2x2(v.x); acc[0] += a * p.x; acc[1] += a * p.y;
    p = bf2x2(v.y); acc[2] += a * p.x; acc[3] += a * p.y;
    p = bf2x2(v.z); acc[4] += a * p.x; acc[5] += a * p.y;
    p = bf2x2(v.w); acc[6] += a * p.x; acc[7] += a * p.y;
}

__global__ __launch_bounds__(256) void k_agg1(const int* __restrict__ rowptr, const int* __restrict__ ssrc,
                                              const float* __restrict__ alpha, const unsigned short* __restrict__ hb,
                                              const float* __restrict__ bias, int Nn, float* __restrict__ out) {
    int gw = (blockIdx.x * blockDim.x + threadIdx.x) >> 6;
    if (gw >= Nn) return;
    int lane = threadIdx.x & 63;
    int sub = lane >> 4, c = lane & 15, head = c >> 3;
    int beg = rowptr[gw], end = rowptr[gw + 1];
    float acc[8] = {};
    int e = beg + sub;
    for (; e + 4 < end; e += 8) {
        int s0 = ssrc[e], s1 = ssrc[e + 4];
        float a0 = alpha[(size_t)e * 2 + head];
        float a1 = alpha[(size_t)(e + 4) * 2 + head];
        uint4 v0 = *(const uint4*)&hb[(size_t)s0 * 128 + c * 8];
        uint4 v1 = *(const uint4*)&hb[(size_t)s1 * 128 + c * 8];
        acc8(acc, v0, a0); acc8(acc, v1, a1);
    }
    for (; e < end; e += 4) {
        int s = ssrc[e];
        float a = alpha[(size_t)e * 2 + head];
        uint4 v = *(const uint4*)&hb[(size_t)s * 128 + c * 8];
        acc8(acc, v, a);
    }
    #pragma unroll
    for (int j = 0; j < 8; j++) {
        acc[j] += __shfl_xor(acc[j], 16);
        acc[j] += __shfl_xor(acc[j], 32);
    }
    if (sub == 0) {
        float4 b0 = *(const float4*)&bias[c * 8];
        float4 b1 = *(const float4*)&bias[c * 8 + 4];
        float4 o0 = make_float4(acc[0] + b0.x, acc[1] + b0.y, acc[2] + b0.z, acc[3] + b0.w);
        float4 o1 = make_float4(acc[4] + b1.x, acc[5] + b1.y, acc[6] + b1.z, acc[7] + b1.w);
        *(float4*)&out[(size_t)gw * 128 + c * 8] = o0;
        *(float4*)&out[(size_t)gw * 128 + c * 8 + 4] = o1;
    }
}

__global__ __launch_bounds__(256) void k_agg2(const int* __restrict__ rowptr, const int* __restrict__ ssrc,
                                              const float* __restrict__ alpha, const unsigned short* __restrict__ hb,
                                              const float* __restrict__ bias, int Nn, float* __restrict__ out) {
    int gw = (blockIdx.x * blockDim.x + threadIdx.x) >> 6;
    if (gw >= Nn) return;
    int lane = threadIdx.x & 63;
    int sub = lane >> 4, c = lane & 15, head = c >> 3;
    int beg = rowptr[gw], end = rowptr[gw + 1];
    float acc[8] = {};
    int e = beg + sub;
    for (; e + 4 < end; e += 8) {
        int s0 = ssrc[e], s1 = ssrc[e + 4];
        float a0 = alpha[(size_t)e * 2 + head];
        float a1 = alpha[(size_t)(e + 4) * 2 + head];
        uint4 v0 = *(const uint4*)&hb[(size_t)s0 * 128 + c * 8];
        uint4 v1 = *(const uint4*)&hb[(size_t)s1 * 128 + c * 8];
        acc8(acc, v0, a0); acc8(acc, v1, a1);
    }
    for (; e < end; e += 4) {
        int s = ssrc[e];
        float a = alpha[(size_t)e * 2 + head];
        uint4 v = *(const uint4*)&hb[(size_t)s * 128 + c * 8];
        acc8(acc, v, a);
    }
    #pragma unroll
    for (int j = 0; j < 8; j++) {
        acc[j] += __shfl_xor(acc[j], 16);
        acc[j] += __shfl_xor(acc[j], 32);
        acc[j] += __shfl_xor(acc[j], 8);   // combine heads
    }
    if (sub == 0 && c < 8) {
        float4 b0 = *(const float4*)&bias[c * 8];
        float4 b1 = *(const float4*)&bias[c * 8 + 4];
        float4 o0 = make_float4(0.5f * acc[0] + b0.x, 0.5f * acc[1] + b0.y, 0.5f * acc[2] + b0.z, 0.5f * acc[3] + b0.w);
        float4 o1 = make_float4(0.5f * acc[4] + b1.x, 0.5f * acc[5] + b1.y, 0.5f * acc[6] + b1.z, 0.5f * acc[7] + b1.w);
        *(float4*)&out[(size_t)gw * 64 + c * 8] = o0;
        *(float4*)&out[(size_t)gw * 64 + c * 8 + 4] = o1;
    }
}

// ---------------- final GEMM [M,64] @ [64,40] + bias, BN affine + ELU fused on A ----------------
__global__ __launch_bounds__(128) void k_gemmf(const float* __restrict__ A, const float* __restrict__ Wf,
                                               const float* __restrict__ bf, const float* __restrict__ st,
                                               int M, float* __restrict__ out) {
    __shared__ float As[128 * 65];
    __shared__ float Bs[64 * 40];
    int t = threadIdx.x;
    int row0 = blockIdx.x * 128;
    for (int i = t; i < 64 * 40; i += 128) Bs[i] = Wf[i];
    for (int i = t; i < 128 * 64; i += 128) {
        int r = i >> 6, k = i & 63;
        int gr = row0 + r;
        float v = 0.f;
        if (gr < M) {
            v = A[(size_t)gr * 64 + k] * st[k] + st[64 + k];
            v = v > 0.f ? v : expm1f(v);
        }
        As[r * 65 + k] = v;
    }
    __syncthreads();
    int cg = t & 3, rg = t >> 2;
    float acc[4][10] = {};
    for (int k = 0; k < 64; k++) {
        float b[10];
        #pragma unroll
        for (int j = 0; j < 10; j++) b[j] = Bs[k * 40 + cg * 10 + j];
        #pragma unroll
        for (int r = 0; r < 4; r++) {
            float a = As[(rg * 4 + r) * 65 + k];
            #pragma unroll
            for (int j = 0; j < 10; j++) acc[r][j] += a * b[j];
        }
    }
    for (int r = 0; r < 4; r++) {
        int gr = row0 + rg * 4 + r;
        if (gr < M) {
            #pragma unroll
            for (int j = 0; j < 10; j++) out[(size_t)gr * 40 + cg * 10 + j] = acc[r][j] + bf[cg * 10 + j];
        }
    }
}

extern "C" void kernel_launch(void* const* d_in, const int* in_sizes, int n_in,
                              void* d_out, int out_size, void* d_ws, size_t ws_size,
                              hipStream_t stream) {
    const float* x     = (const float*)d_in[0];
    const int*   ei    = (const int*)d_in[1];
    const float* bn0_g = (const float*)d_in[2];
    const float* bn0_b = (const float*)d_in[3];
    const float* W1    = (const float*)d_in[4];
    const float* a1s   = (const float*)d_in[5];
    const float* a1d   = (const float*)d_in[6];
    const float* b1    = (const float*)d_in[7];
    const float* bn1_g = (const float*)d_in[8];
    const float* bn1_b = (const float*)d_in[9];
    const float* W2    = (const float*)d_in[10];
    const float* a2s   = (const float*)d_in[11];
    const float* a2d   = (const float*)d_in[12];
    const float* b2    = (const float*)d_in[13];
    const float* bn2_g = (const float*)d_in[14];
    const float* bn2_b = (const float*)d_in[15];
    const float* Wf    = (const float*)d_in[16];
    const float* bf    = (const float*)d_in[17];
    float* out = (float*)d_out;

    const int N  = in_sizes[0] / 128;
    const int E  = in_sizes[1] / 2;
    const int ET = E + N;

    char* ws = (char*)d_ws;
    size_t off = 0;
    auto alloc = [&](size_t bytes) -> char* {
        char* p = ws + off;
        off = (off + bytes + 255) & ~(size_t)255;
        return p;
    };
    int*   cnt    = (int*)alloc((size_t)N * 4);
    int*   rowptr = (int*)alloc((size_t)(N + 1) * 4);
    int*   cursor = (int*)alloc((size_t)N * 4);
    int*   ssrc   = (int*)alloc((size_t)ET * 4);
    float* alpha  = (float*)alloc((size_t)ET * 2 * 4);
    float* abuf   = (float*)alloc((size_t)N * 128 * 4);
    unsigned short* abf = (unsigned short*)alloc((size_t)N * 128 * 2);
    unsigned short* hb  = (unsigned short*)alloc((size_t)N * 128 * 2);
    unsigned short* wt  = (unsigned short*)alloc((size_t)128 * 128 * 2);
    float* als    = (float*)alloc((size_t)N * 2 * 4);
    float* ald    = (float*)alloc((size_t)N * 2 * 4);
    int*   part   = (int*)alloc(1024 * 4);
    float* sums   = (float*)alloc(256 * 4);
    float* st     = (float*)alloc(256 * 4);

    const int tb = 256;
    const int egrid = (ET + tb - 1) / tb;
    const int wgrid = ((size_t)N * 64 + tb - 1) / tb;
    const int pgrid = ((size_t)N * 16 + tb - 1) / tb;
    const int ggrid = (N + 63) / 64;
    const int nscan = (N + 1023) / 1024;

    // CSR build (graph identical for both layers)
    hipMemsetAsync(cnt, 0, (size_t)N * 4, stream);
    k_hist<<<egrid, tb, 0, stream>>>(ei, E, N, cnt);
    k_part<<<nscan, 1024, 0, stream>>>(cnt, N, part);
    k_scanp<<<1, 64, 0, stream>>>(part, nscan, N, rowptr);
    k_scan2<<<nscan, 1024, 0, stream>>>(cnt, N, part, rowptr, cursor);
    k_fill<<<egrid, tb, 0, stream>>>(ei, E, N, cursor, ssrc);

    // BN0
    hipMemsetAsync(sums, 0, 256 * 4, stream);
    k_bnstat<<<(N + 63) / 64, 128, 0, stream>>>(x, N, 128, 64, sums);
    k_bnfin<<<1, 128, 0, stream>>>(sums, N, 128, bn0_g, bn0_b, st);

    // layer 1
    k_prep<<<pgrid, tb, 0, stream>>>(x, st, N, 0, abf);
    k_wt<<<64, tb, 0, stream>>>(W1, wt);
    k_mfma<<<ggrid, tb, 0, stream>>>(abf, wt, a1s, a1d, N, hb, als, ald);
    k_attn<<<wgrid, tb, 0, stream>>>(rowptr, ssrc, als, ald, N, alpha);
    k_agg1<<<wgrid, tb, 0, stream>>>(rowptr, ssrc, alpha, hb, b1, N, abuf);

    // BN1
    hipMemsetAsync(sums, 0, 256 * 4, stream);
    k_bnstat<<<(N + 63) / 64, 128, 0, stream>>>(abuf, N, 128, 64, sums);
    k_bnfin<<<1, 128, 0, stream>>>(sums, N, 128, bn1_g, bn1_b, st);

    // layer 2
    k_prep<<<pgrid, tb, 0, stream>>>(abuf, st, N, 1, abf);
    k_wt<<<64, tb, 0, stream>>>(W2, wt);
    k_mfma<<<ggrid, tb, 0, stream>>>(abf, wt, a2s, a2d, N, hb, als, ald);
    k_attn<<<wgrid, tb, 0, stream>>>(rowptr, ssrc, als, ald, N, alpha);
    k_agg2<<<wgrid, tb, 0, stream>>>(rowptr, ssrc, alpha, hb, b2, N, abuf);

    // BN2
    hipMemsetAsync(sums, 0, 256 * 4, stream);
    k_bnstat<<<(N + 63) / 64, 64, 0, stream>>>(abuf, N, 64, 64, sums);
    k_bnfin<<<1, 64, 0, stream>>>(sums, N, 64, bn2_g, bn2_b, st);

    // final linear
    k_gemmf<<<(N + 127) / 128, 128, 0, stream>>>(abuf, Wf, bf, st, N, out);
}

// Round 6
// 424.416 us; speedup vs baseline: 1.7995x; 1.1170x over previous
//
#include <hip/hip_runtime.h>

// GAT 2-layer + BN + final linear on MI355X.
// R6: fix R5's UB — shfl-based alpha distribution now runs with a wave-uniform
// trip count (shfls always full-wave; gathers predicated), so no reads from
// inactive lanes. rank/alpha aliased into dead ws regions (footprint ~56MB).

#define NEG_SLOPE 0.2f
#define BN_EPS 1e-5f

typedef short bf16x8 __attribute__((ext_vector_type(8)));
typedef float f32x4 __attribute__((ext_vector_type(4)));

static __device__ __forceinline__ unsigned short f2bf(float f) {
    union { float f; unsigned u; } v; v.f = f;
    unsigned r = v.u + 0x7FFF + ((v.u >> 16) & 1);
    return (unsigned short)(r >> 16);
}
static __device__ __forceinline__ float2 bf2x2(unsigned v) {
    union { unsigned u; float f; } a, b;
    a.u = v << 16; b.u = v & 0xffff0000u;
    return make_float2(a.f, b.f);
}

// ---------------- CSR build ----------------
// one atomic pass: histogram AND per-edge rank (the atomic's return value)
__global__ void k_rank(const int* __restrict__ ei, int E, int Nn,
                       int* __restrict__ cnt, int* __restrict__ rank) {
    int i = blockIdx.x * blockDim.x + threadIdx.x;
    if (i >= E + Nn) return;
    int d = (i < E) ? ei[E + i] : (i - E);
    rank[i] = atomicAdd(&cnt[d], 1);
}

// phase 1: per-block (1024-tile) reduction
__global__ __launch_bounds__(1024) void k_part(const int* __restrict__ cnt, int Nn,
                                               int* __restrict__ part) {
    __shared__ int ws[16];
    int t = threadIdx.x, lane = t & 63, w = t >> 6;
    int i = blockIdx.x * 1024 + t;
    int v = (i < Nn) ? cnt[i] : 0;
    #pragma unroll
    for (int off = 32; off; off >>= 1) v += __shfl_xor(v, off);
    if (lane == 0) ws[w] = v;
    __syncthreads();
    if (t < 16) {
        int s = ws[t];
        #pragma unroll
        for (int off = 8; off; off >>= 1) s += __shfl_xor(s, off);
        if (t == 0) part[blockIdx.x] = s;
    }
}

// phase 2: single-wave exclusive scan of partials; writes total to rowptr[Nn]
__global__ __launch_bounds__(64) void k_scanp(int* __restrict__ part, int nb,
                                              int Nn, int* __restrict__ rowptr) {
    int lane = threadIdx.x;
    int carry = 0;
    for (int base = 0; base < nb; base += 64) {
        int i = base + lane;
        int v = (i < nb) ? part[i] : 0;
        int x = v;
        #pragma unroll
        for (int off = 1; off < 64; off <<= 1) {
            int y = __shfl_up(x, off);
            if (lane >= off) x += y;
        }
        if (i < nb) part[i] = carry + x - v;     // exclusive
        carry += __shfl(x, 63);
    }
    if (lane == 0) rowptr[Nn] = carry;
}

// phase 3: block-local scan + block offset
__global__ __launch_bounds__(1024) void k_scan2(const int* __restrict__ cnt, int Nn,
                                                const int* __restrict__ part,
                                                int* __restrict__ rowptr) {
    __shared__ int wsum[16];
    int t = threadIdx.x, lane = t & 63, w = t >> 6;
    int i = blockIdx.x * 1024 + t;
    int v = (i < Nn) ? cnt[i] : 0;
    int x = v;
    #pragma unroll
    for (int off = 1; off < 64; off <<= 1) {
        int y = __shfl_up(x, off);
        if (lane >= off) x += y;
    }
    if (lane == 63) wsum[w] = x;
    __syncthreads();
    if (w == 0) {
        int val = (lane < 16) ? wsum[lane] : 0;
        int xs = val;
        #pragma unroll
        for (int off = 1; off < 16; off <<= 1) {
            int y = __shfl_up(xs, off);
            if (lane >= off) xs += y;
        }
        if (lane < 16) wsum[lane] = xs - val;    // exclusive wave offsets
    }
    __syncthreads();
    if (i < Nn) rowptr[i] = part[blockIdx.x] + wsum[w] + (x - v);
}

// atomic-free fill: pos = rowptr[d] + rank[i]
__global__ void k_fill2(const int* __restrict__ ei, const int* __restrict__ rank,
                        const int* __restrict__ rowptr, int E, int Nn,
                        int* __restrict__ ssrc) {
    int i = blockIdx.x * blockDim.x + threadIdx.x;
    if (i >= E + Nn) return;
    int s, d;
    if (i < E) { s = ei[i]; d = ei[E + i]; }
    else       { s = i - E; d = s; }
    ssrc[rowptr[d] + rank[i]] = s;
}

// ---------------- BatchNorm stats ----------------
__global__ void k_bnstat(const float* __restrict__ x, int M, int C, int rows,
                         float* __restrict__ sums) {
    int c = threadIdx.x;
    int r0 = blockIdx.x * rows;
    int r1 = min(M, r0 + rows);
    float s = 0.f, s2 = 0.f;
    for (int r = r0; r < r1; r++) {
        float v = x[(size_t)r * C + c];
        s += v; s2 += v * v;
    }
    atomicAdd(&sums[c], s);
    atomicAdd(&sums[C + c], s2);
}

__global__ void k_bnfin(const float* __restrict__ sums, int M, int C,
                        const float* __restrict__ g, const float* __restrict__ b,
                        float* __restrict__ st) {
    int c = threadIdx.x;
    if (c < C) {
        float mu = sums[c] / (float)M;
        float var = sums[C + c] / (float)M - mu * mu;
        float s = g[c] * rsqrtf(var + BN_EPS);
        st[c] = s;
        st[C + c] = b[c] - mu * s;
    }
}

// ---------------- prepass: fp32 -> BN affine (+ELU) -> bf16, C=128 ----------------
__global__ __launch_bounds__(256) void k_prep(const float* __restrict__ in, const float* __restrict__ st,
                                              int M, int elu, unsigned short* __restrict__ outb) {
    int tid = blockIdx.x * 256 + threadIdx.x;
    size_t idx = (size_t)tid * 8;
    if (idx >= (size_t)M * 128) return;
    int ch = (int)(idx & 127);
    float4 v0 = *(const float4*)&in[idx];
    float4 v1 = *(const float4*)&in[idx + 4];
    float4 s0 = *(const float4*)&st[ch];
    float4 s1 = *(const float4*)&st[ch + 4];
    float4 t0 = *(const float4*)&st[128 + ch];
    float4 t1 = *(const float4*)&st[128 + ch + 4];
    float a[8] = {v0.x*s0.x+t0.x, v0.y*s0.y+t0.y, v0.z*s0.z+t0.z, v0.w*s0.w+t0.w,
                  v1.x*s1.x+t1.x, v1.y*s1.y+t1.y, v1.z*s1.z+t1.z, v1.w*s1.w+t1.w};
    if (elu) {
        #pragma unroll
        for (int j = 0; j < 8; j++) a[j] = a[j] > 0.f ? a[j] : expm1f(a[j]);
    }
    uint4 p;
    p.x = ((unsigned)f2bf(a[1]) << 16) | f2bf(a[0]);
    p.y = ((unsigned)f2bf(a[3]) << 16) | f2bf(a[2]);
    p.z = ((unsigned)f2bf(a[5]) << 16) | f2bf(a[4]);
    p.w = ((unsigned)f2bf(a[7]) << 16) | f2bf(a[6]);
    *(uint4*)&outb[idx] = p;
}

// ---------------- W^T bf16: wt[n][k] = W[k][n], 128x128 ----------------
__global__ __launch_bounds__(256) void k_wt(const float* __restrict__ W, unsigned short* __restrict__ wt) {
    int idx = blockIdx.x * 256 + threadIdx.x;
    if (idx >= 128 * 128) return;
    int n = idx >> 7, k = idx & 127;
    wt[idx] = f2bf(W[k * 128 + n]);
}

// ---------------- MFMA GEMM [M,128]@[128,128] -> bf16 hb; epilogue: als/ald dot ----------------
__global__ __launch_bounds__(256) void k_mfma(
    const unsigned short* __restrict__ abf, const unsigned short* __restrict__ wt,
    const float* __restrict__ asrc, const float* __restrict__ adst, int M,
    unsigned short* __restrict__ hb, float* __restrict__ als, float* __restrict__ ald) {
    __shared__ unsigned short As[64 * 136];
    __shared__ unsigned short Bs[128 * 136];
    const int t = threadIdx.x;
    const int w = t >> 6, lane = t & 63;
    const int c = lane & 15, q = lane >> 4;
    const int row0 = blockIdx.x * 64;

    #pragma unroll
    for (int i = 0; i < 4; i++) {                 // A tile: 64 rows x 128k
        int idx = t + i * 256;
        int r = idx >> 4, ch = idx & 15;
        uint4 v = make_uint4(0, 0, 0, 0);
        if (row0 + r < M) v = *(const uint4*)&abf[(size_t)(row0 + r) * 128 + ch * 8];
        *(uint4*)&As[r * 136 + ch * 8] = v;
    }
    #pragma unroll
    for (int i = 0; i < 8; i++) {                 // B tile: 128 n x 128 k (W^T)
        int idx = t + i * 256;
        int r = idx >> 4, ch = idx & 15;
        *(uint4*)&Bs[r * 136 + ch * 8] = *(const uint4*)&wt[(size_t)r * 128 + ch * 8];
    }
    __syncthreads();

    f32x4 acc[8] = {};
    #pragma unroll
    for (int ks = 0; ks < 4; ks++) {
        bf16x8 a = *(bf16x8*)&As[(w * 16 + c) * 136 + (ks * 4 + q) * 8];
        #pragma unroll
        for (int tl = 0; tl < 8; tl++) {
            bf16x8 b = *(bf16x8*)&Bs[(tl * 16 + c) * 136 + (ks * 4 + q) * 8];
            acc[tl] = __builtin_amdgcn_mfma_f32_16x16x32_bf16(a, b, acc[tl], 0, 0, 0);
        }
    }

    // epilogue 1: bf16 h store. C/D: col = c, row = q*4 + reg.
    #pragma unroll
    for (int reg = 0; reg < 4; reg++) {
        int grow = row0 + w * 16 + q * 4 + reg;
        if (grow < M) {
            #pragma unroll
            for (int tl = 0; tl < 8; tl++)
                hb[(size_t)grow * 128 + tl * 16 + c] = f2bf(acc[tl][reg]);
        }
    }

    // epilogue 2: attention logits als/ald
    float as_[8], ad_[8];
    #pragma unroll
    for (int tl = 0; tl < 8; tl++) { as_[tl] = asrc[tl * 16 + c]; ad_[tl] = adst[tl * 16 + c]; }
    #pragma unroll
    for (int reg = 0; reg < 4; reg++) {
        float s0 = 0.f, s1 = 0.f, d0 = 0.f, d1 = 0.f;
        #pragma unroll
        for (int tl = 0; tl < 4; tl++) { s0 += acc[tl][reg] * as_[tl]; d0 += acc[tl][reg] * ad_[tl]; }
        #pragma unroll
        for (int tl = 4; tl < 8; tl++) { s1 += acc[tl][reg] * as_[tl]; d1 += acc[tl][reg] * ad_[tl]; }
        #pragma unroll
        for (int off = 1; off < 16; off <<= 1) {
            s0 += __shfl_xor(s0, off); s1 += __shfl_xor(s1, off);
            d0 += __shfl_xor(d0, off); d1 += __shfl_xor(d1, off);
        }
        int grow = row0 + w * 16 + q * 4 + reg;
        if (c == 0 && grow < M) {
            *(float2*)&als[(size_t)grow * 2] = make_float2(s0, s1);
            *(float2*)&ald[(size_t)grow * 2] = make_float2(d0, d1);
        }
    }
}

// ---------------- fused softmax + aggregation: wave per dst node ----------------
// pass 1 (lane = edge): alpha in registers. pass 2: UNIFORM trip count; shfls
// full-wave (never under divergence); gather+acc predicated by j < deg.
static __device__ __forceinline__ void acc8(float* acc, uint4 v, float a) {
    float2 p;
    p = bf2x2(v.x); acc[0] += a * p.x; acc[1] += a * p.y;
    p = bf2x2(v.y); acc[2] += a * p.x; acc[3] += a * p.y;
    p = bf2x2(v.z); acc[4] += a * p.x; acc[5] += a * p.y;
    p = bf2x2(v.w); acc[6] += a * p.x; acc[7] += a * p.y;
}

template <int MEAN>
static __device__ __forceinline__ void attnagg(
    const int* __restrict__ rowptr, const int* __restrict__ ssrc,
    const float* __restrict__ als, const float* __restrict__ ald,
    float* __restrict__ alpha, const unsigned short* __restrict__ hb,
    const float* __restrict__ bias, int Nn, float* __restrict__ out) {
    int gw = (blockIdx.x * blockDim.x + threadIdx.x) >> 6;
    if (gw >= Nn) return;
    int lane = threadIdx.x & 63;
    int sub = lane >> 4, c = lane & 15, head = c >> 3;
    int beg = rowptr[gw], end = rowptr[gw + 1];
    int deg = end - beg;
    float2 dv = *(const float2*)&ald[(size_t)gw * 2];
    float acc[8] = {};

    if (deg <= 64) {
        // pass 1: per-lane alpha (lane = edge index within segment)
        bool on = lane < deg;
        int eidx = beg + (on ? lane : 0);
        int sreg = ssrc[eidx];
        float2 av = *(const float2*)&als[(size_t)sreg * 2];
        float v0 = av.x + dv.x; v0 = v0 > 0.f ? v0 : NEG_SLOPE * v0;
        float v1 = av.y + dv.y; v1 = v1 > 0.f ? v1 : NEG_SLOPE * v1;
        float m0 = on ? v0 : -1e30f, m1 = on ? v1 : -1e30f;
        #pragma unroll
        for (int off = 32; off; off >>= 1) {
            m0 = fmaxf(m0, __shfl_xor(m0, off));
            m1 = fmaxf(m1, __shfl_xor(m1, off));
        }
        float p0 = on ? __expf(v0 - m0) : 0.f;
        float p1 = on ? __expf(v1 - m1) : 0.f;
        float t0 = p0, t1 = p1;
        #pragma unroll
        for (int off = 32; off; off >>= 1) {
            t0 += __shfl_xor(t0, off);
            t1 += __shfl_xor(t1, off);
        }
        float al0 = p0 / t0, al1 = p1 / t1;

        // pass 2: uniform loop; lane handles edges j = it*4 + sub (2 per iter)
        int nit = (deg + 3) >> 2;                 // wave-uniform
        for (int it = 0; it < nit; it += 2) {
            int j0 = it * 4 + sub;                // <= 62
            int j1 = j0 + 4;                      // <= 63 (wait covers via pred)
            int sa = __shfl(sreg, j0);
            int sb = __shfl(sreg, j1 & 63);
            float a0a = __shfl(al0, j0), a1a = __shfl(al1, j0);
            float a0b = __shfl(al0, j1 & 63), a1b = __shfl(al1, j1 & 63);
            float aa = head ? a1a : a0a;
            float ab = head ? a1b : a0b;
            if (j0 < deg) {
                uint4 va = *(const uint4*)&hb[(size_t)sa * 128 + c * 8];
                acc8(acc, va, aa);
            }
            if (j1 < deg) {
                uint4 vb = *(const uint4*)&hb[(size_t)sb * 128 + c * 8];
                acc8(acc, vb, ab);
            }
        }
    } else {
        // fallback (deg > 64, ~never for random graphs): alpha via global buffer
        float d0 = dv.x, d1 = dv.y;
        float m0 = -1e30f, m1 = -1e30f;
        for (int e = beg + lane; e < end; e += 64) {
            int s = ssrc[e];
            float v0 = als[s * 2] + d0;     v0 = v0 > 0.f ? v0 : NEG_SLOPE * v0;
            float v1 = als[s * 2 + 1] + d1; v1 = v1 > 0.f ? v1 : NEG_SLOPE * v1;
            m0 = fmaxf(m0, v0); m1 = fmaxf(m1, v1);
        }
        #pragma unroll
        for (int off = 32; off; off >>= 1) {
            m0 = fmaxf(m0, __shfl_xor(m0, off));
            m1 = fmaxf(m1, __shfl_xor(m1, off));
        }
        float t0 = 0.f, t1 = 0.f;
        for (int e = beg + lane; e < end; e += 64) {
            int s = ssrc[e];
            float v0 = als[s * 2] + d0;     v0 = v0 > 0.f ? v0 : NEG_SLOPE * v0;
            float v1 = als[s * 2 + 1] + d1; v1 = v1 > 0.f ? v1 : NEG_SLOPE * v1;
            float p0 = __expf(v0 - m0), p1 = __expf(v1 - m1);
            alpha[e * 2] = p0; alpha[e * 2 + 1] = p1;
            t0 += p0; t1 += p1;
        }
        #pragma unroll
        for (int off = 32; off; off >>= 1) {
            t0 += __shfl_xor(t0, off);
            t1 += __shfl_xor(t1, off);
        }
        float i0 = 1.f / t0, i1 = 1.f / t1;
        for (int e = beg + sub; e < end; e += 4) {
            int s = ssrc[e];
            float a = (head ? alpha[(size_t)e * 2 + 1] * i1 : alpha[(size_t)e * 2] * i0);
            uint4 v = *(const uint4*)&hb[(size_t)s * 128 + c * 8];
            acc8(acc, v, a);
        }
    }

    #pragma unroll
    for (int j2 = 0; j2 < 8; j2++) {
        acc[j2] += __shfl_xor(acc[j2], 16);
        acc[j2] += __shfl_xor(acc[j2], 32);
        if (MEAN) acc[j2] += __shfl_xor(acc[j2], 8);   // combine heads
    }
    if (MEAN) {
        if (sub == 0 && c < 8) {
            float4 b0 = *(const float4*)&bias[c * 8];
            float4 b1 = *(const float4*)&bias[c * 8 + 4];
            float4 o0 = make_float4(0.5f * acc[0] + b0.x, 0.5f * acc[1] + b0.y, 0.5f * acc[2] + b0.z, 0.5f * acc[3] + b0.w);
            float4 o1 = make_float4(0.5f * acc[4] + b1.x, 0.5f * acc[5] + b1.y, 0.5f * acc[6] + b1.z, 0.5f * acc[7] + b1.w);
            *(float4*)&out[(size_t)gw * 64 + c * 8] = o0;
            *(float4*)&out[(size_t)gw * 64 + c * 8 + 4] = o1;
        }
    } else {
        if (sub == 0) {
            float4 b0 = *(const float4*)&bias[c * 8];
            float4 b1 = *(const float4*)&bias[c * 8 + 4];
            float4 o0 = make_float4(acc[0] + b0.x, acc[1] + b0.y, acc[2] + b0.z, acc[3] + b0.w);
            float4 o1 = make_float4(acc[4] + b1.x, acc[5] + b1.y, acc[6] + b1.z, acc[7] + b1.w);
            *(float4*)&out[(size_t)gw * 128 + c * 8] = o0;
            *(float4*)&out[(size_t)gw * 128 + c * 8 + 4] = o1;
        }
    }
}

__global__ __launch_bounds__(256) void k_attnagg1(const int* __restrict__ rowptr, const int* __restrict__ ssrc,
                                                  const float* __restrict__ als, const float* __restrict__ ald,
                                                  float* __restrict__ alpha, const unsigned short* __restrict__ hb,
                                                  const float* __restrict__ bias, int Nn, float* __restrict__ out) {
    attnagg<0>(rowptr, ssrc, als, ald, alpha, hb, bias, Nn, out);
}

__global__ __launch_bounds__(256) void k_attnagg2(const int* __restrict__ rowptr, const int* __restrict__ ssrc,
                                                  const float* __restrict__ als, const float* __restrict__ ald,
                                                  float* __restrict__ alpha, const unsigned short* __restrict__ hb,
                                                  const float* __restrict__ bias, int Nn, float* __restrict__ out) {
    attnagg<1>(rowptr, ssrc, als, ald, alpha, hb, bias, Nn, out);
}

// ---------------- final GEMM [M,64] @ [64,40] + bias, BN affine + ELU fused on A ----------------
__global__ __launch_bounds__(128) void k_gemmf(const float* __restrict__ A, const float* __restrict__ Wf,
                                               const float* __restrict__ bf, const float* __restrict__ st,
                                               int M, float* __restrict__ out) {
    __shared__ float As[128 * 65];
    __shared__ float Bs[64 * 40];
    int t = threadIdx.x;
    int row0 = blockIdx.x * 128;
    for (int i = t; i < 64 * 40; i += 128) Bs[i] = Wf[i];
    for (int i = t; i < 128 * 64; i += 128) {
        int r = i >> 6, k = i & 63;
        int gr = row0 + r;
        float v = 0.f;
        if (gr < M) {
            v = A[(size_t)gr * 64 + k] * st[k] + st[64 + k];
            v = v > 0.f ? v : expm1f(v);
        }
        As[r * 65 + k] = v;
    }
    __syncthreads();
    int cg = t & 3, rg = t >> 2;
    float acc[4][10] = {};
    for (int k = 0; k < 64; k++) {
        float b[10];
        #pragma unroll
        for (int j = 0; j < 10; j++) b[j] = Bs[k * 40 + cg * 10 + j];
        #pragma unroll
        for (int r = 0; r < 4; r++) {
            float a = As[(rg * 4 + r) * 65 + k];
            #pragma unroll
            for (int j = 0; j < 10; j++) acc[r][j] += a * b[j];
        }
    }
    for (int r = 0; r < 4; r++) {
        int gr = row0 + rg * 4 + r;
        if (gr < M) {
            #pragma unroll
            for (int j = 0; j < 10; j++) out[(size_t)gr * 40 + cg * 10 + j] = acc[r][j] + bf[cg * 10 + j];
        }
    }
}

extern "C" void kernel_launch(void* const* d_in, const int* in_sizes, int n_in,
                              void* d_out, int out_size, void* d_ws, size_t ws_size,
                              hipStream_t stream) {
    const float* x     = (const float*)d_in[0];
    const int*   ei    = (const int*)d_in[1];
    const float* bn0_g = (const float*)d_in[2];
    const float* bn0_b = (const float*)d_in[3];
    const float* W1    = (const float*)d_in[4];
    const float* a1s   = (const float*)d_in[5];
    const float* a1d   = (const float*)d_in[6];
    const float* b1    = (const float*)d_in[7];
    const float* bn1_g = (const float*)d_in[8];
    const float* bn1_b = (const float*)d_in[9];
    const float* W2    = (const float*)d_in[10];
    const float* a2s   = (const float*)d_in[11];
    const float* a2d   = (const float*)d_in[12];
    const float* b2    = (const float*)d_in[13];
    const float* bn2_g = (const float*)d_in[14];
    const float* bn2_b = (const float*)d_in[15];
    const float* Wf    = (const float*)d_in[16];
    const float* bf    = (const float*)d_in[17];
    float* out = (float*)d_out;

    const int N  = in_sizes[0] / 128;
    const int E  = in_sizes[1] / 2;
    const int ET = E + N;

    char* ws = (char*)d_ws;
    size_t off = 0;
    auto alloc = [&](size_t bytes) -> char* {
        char* p = ws + off;
        off = (off + bytes + 255) & ~(size_t)255;
        return p;
    };
    int*   cnt    = (int*)alloc((size_t)N * 4);
    int*   rowptr = (int*)alloc((size_t)(N + 1) * 4);
    int*   ssrc   = (int*)alloc((size_t)ET * 4);
    float* abuf   = (float*)alloc((size_t)N * 128 * 4);
    unsigned short* abf = (unsigned short*)alloc((size_t)N * 128 * 2);
    unsigned short* hb  = (unsigned short*)alloc((size_t)N * 128 * 2);
    unsigned short* wt  = (unsigned short*)alloc((size_t)128 * 128 * 2);
    float* als    = (float*)alloc((size_t)N * 2 * 4);
    float* ald    = (float*)alloc((size_t)N * 2 * 4);
    int*   part   = (int*)alloc(1024 * 4);
    float* sums   = (float*)alloc(256 * 4);
    float* st     = (float*)alloc(256 * 4);
    // aliases into dead regions (stream-ordered safety):
    //   rank: live k_rank -> k_fill2; hb first written later (k_mfma L1)
    //   alpha (deg>64 fallback only): live inside attnagg; abf dead there
    int*   rank   = (int*)hb;
    float* alpha  = (float*)abf;

    const int tb = 256;
    const int egrid = (ET + tb - 1) / tb;
    const int wgrid = ((size_t)N * 64 + tb - 1) / tb;
    const int pgrid = ((size_t)N * 16 + tb - 1) / tb;
    const int ggrid = (N + 63) / 64;
    const int nscan = (N + 1023) / 1024;

    // CSR build (graph identical for both layers)
    hipMemsetAsync(cnt, 0, (size_t)N * 4, stream);
    k_rank<<<egrid, tb, 0, stream>>>(ei, E, N, cnt, rank);
    k_part<<<nscan, 1024, 0, stream>>>(cnt, N, part);
    k_scanp<<<1, 64, 0, stream>>>(part, nscan, N, rowptr);
    k_scan2<<<nscan, 1024, 0, stream>>>(cnt, N, part, rowptr);
    k_fill2<<<egrid, tb, 0, stream>>>(ei, rank, rowptr, E, N, ssrc);

    // BN0
    hipMemsetAsync(sums, 0, 256 * 4, stream);
    k_bnstat<<<(N + 63) / 64, 128, 0, stream>>>(x, N, 128, 64, sums);
    k_bnfin<<<1, 128, 0, stream>>>(sums, N, 128, bn0_g, bn0_b, st);

    // layer 1
    k_prep<<<pgrid, tb, 0, stream>>>(x, st, N, 0, abf);
    k_wt<<<64, tb, 0, stream>>>(W1, wt);
    k_mfma<<<ggrid, tb, 0, stream>>>(abf, wt, a1s, a1d, N, hb, als, ald);
    k_attnagg1<<<wgrid, tb, 0, stream>>>(rowptr, ssrc, als, ald, alpha, hb, b1, N, abuf);

    // BN1
    hipMemsetAsync(sums, 0, 256 * 4, stream);
    k_bnstat<<<(N + 63) / 64, 128, 0, stream>>>(abuf, N, 128, 64, sums);
    k_bnfin<<<1, 128, 0, stream>>>(sums, N, 128, bn1_g, bn1_b, st);

    // layer 2
    k_prep<<<pgrid, tb, 0, stream>>>(abuf, st, N, 1, abf);
    k_wt<<<64, tb, 0, stream>>>(W2, wt);
    k_mfma<<<ggrid, tb, 0, stream>>>(abf, wt, a2s, a2d, N, hb, als, ald);
    k_attnagg2<<<wgrid, tb, 0, stream>>>(rowptr, ssrc, als, ald, alpha, hb, b2, N, abuf);

    // BN2
    hipMemsetAsync(sums, 0, 256 * 4, stream);
    k_bnstat<<<(N + 63) / 64, 64, 0, stream>>>(abuf, N, 64, 64, sums);
    k_bnfin<<<1, 64, 0, stream>>>(sums, N, 64, bn2_g, bn2_b, st);

    // final linear
    k_gemmf<<<(N + 127) / 128, 128, 0, stream>>>(abuf, Wf, bf, st, N, out);
}

// Round 7
// 341.145 us; speedup vs baseline: 2.2388x; 1.2441x over previous
//
#include <hip/hip_runtime.h>

// GAT 2-layer + BN + final linear on MI355X.
// R7: vectorized BN stats (float4 streaming + shfl/LDS reduce, was 46us
// latency-bound scalar), attnagg pass-2 unroll-4 (more gather MLP),
// single memset for all BN sum buffers.

#define NEG_SLOPE 0.2f
#define BN_EPS 1e-5f

typedef short bf16x8 __attribute__((ext_vector_type(8)));
typedef float f32x4 __attribute__((ext_vector_type(4)));

static __device__ __forceinline__ unsigned short f2bf(float f) {
    union { float f; unsigned u; } v; v.f = f;
    unsigned r = v.u + 0x7FFF + ((v.u >> 16) & 1);
    return (unsigned short)(r >> 16);
}
static __device__ __forceinline__ float2 bf2x2(unsigned v) {
    union { unsigned u; float f; } a, b;
    a.u = v << 16; b.u = v & 0xffff0000u;
    return make_float2(a.f, b.f);
}

// ---------------- CSR build ----------------
__global__ void k_rank(const int* __restrict__ ei, int E, int Nn,
                       int* __restrict__ cnt, int* __restrict__ rank) {
    int i = blockIdx.x * blockDim.x + threadIdx.x;
    if (i >= E + Nn) return;
    int d = (i < E) ? ei[E + i] : (i - E);
    rank[i] = atomicAdd(&cnt[d], 1);
}

__global__ __launch_bounds__(1024) void k_part(const int* __restrict__ cnt, int Nn,
                                               int* __restrict__ part) {
    __shared__ int ws[16];
    int t = threadIdx.x, lane = t & 63, w = t >> 6;
    int i = blockIdx.x * 1024 + t;
    int v = (i < Nn) ? cnt[i] : 0;
    #pragma unroll
    for (int off = 32; off; off >>= 1) v += __shfl_xor(v, off);
    if (lane == 0) ws[w] = v;
    __syncthreads();
    if (t < 16) {
        int s = ws[t];
        #pragma unroll
        for (int off = 8; off; off >>= 1) s += __shfl_xor(s, off);
        if (t == 0) part[blockIdx.x] = s;
    }
}

__global__ __launch_bounds__(64) void k_scanp(int* __restrict__ part, int nb,
                                              int Nn, int* __restrict__ rowptr) {
    int lane = threadIdx.x;
    int carry = 0;
    for (int base = 0; base < nb; base += 64) {
        int i = base + lane;
        int v = (i < nb) ? part[i] : 0;
        int x = v;
        #pragma unroll
        for (int off = 1; off < 64; off <<= 1) {
            int y = __shfl_up(x, off);
            if (lane >= off) x += y;
        }
        if (i < nb) part[i] = carry + x - v;
        carry += __shfl(x, 63);
    }
    if (lane == 0) rowptr[Nn] = carry;
}

__global__ __launch_bounds__(1024) void k_scan2(const int* __restrict__ cnt, int Nn,
                                                const int* __restrict__ part,
                                                int* __restrict__ rowptr) {
    __shared__ int wsum[16];
    int t = threadIdx.x, lane = t & 63, w = t >> 6;
    int i = blockIdx.x * 1024 + t;
    int v = (i < Nn) ? cnt[i] : 0;
    int x = v;
    #pragma unroll
    for (int off = 1; off < 64; off <<= 1) {
        int y = __shfl_up(x, off);
        if (lane >= off) x += y;
    }
    if (lane == 63) wsum[w] = x;
    __syncthreads();
    if (w == 0) {
        int val = (lane < 16) ? wsum[lane] : 0;
        int xs = val;
        #pragma unroll
        for (int off = 1; off < 16; off <<= 1) {
            int y = __shfl_up(xs, off);
            if (lane >= off) xs += y;
        }
        if (lane < 16) wsum[lane] = xs - val;
    }
    __syncthreads();
    if (i < Nn) rowptr[i] = part[blockIdx.x] + wsum[w] + (x - v);
}

__global__ void k_fill2(const int* __restrict__ ei, const int* __restrict__ rank,
                        const int* __restrict__ rowptr, int E, int Nn,
                        int* __restrict__ ssrc) {
    int i = blockIdx.x * blockDim.x + threadIdx.x;
    if (i >= E + Nn) return;
    int s, d;
    if (i < E) { s = ei[i]; d = ei[E + i]; }
    else       { s = i - E; d = s; }
    ssrc[rowptr[d] + rank[i]] = s;
}

// ---------------- BatchNorm stats: vectorized streaming ----------------
// 256 threads; C/4 threads cover one row (float4/lane); 1024/C rows in flight.
// shfl combines row slots within a wave; LDS combines waves; 2C atomics/block.
template <int C>
__global__ __launch_bounds__(256) void k_bnstat2(const float* __restrict__ x, int M,
                                                 int rowsPerBlock, float* __restrict__ sums) {
    constexpr int TPR = C / 4;             // threads per row
    constexpr int RS  = 256 / TPR;         // rows in flight
    __shared__ float red[4][2 * C];
    const int t = threadIdx.x;
    const int cg = t % TPR, rg = t / TPR, w = t >> 6, lane = t & 63;
    int r0 = blockIdx.x * rowsPerBlock + rg;
    int r1 = min(M, blockIdx.x * rowsPerBlock + rowsPerBlock);
    float4 s = make_float4(0, 0, 0, 0), q = make_float4(0, 0, 0, 0);
    #pragma unroll 4
    for (int r = r0; r < r1; r += RS) {
        float4 v = *(const float4*)&x[(size_t)r * C + cg * 4];
        s.x += v.x; s.y += v.y; s.z += v.z; s.w += v.w;
        q.x += v.x * v.x; q.y += v.y * v.y; q.z += v.z * v.z; q.w += v.w * v.w;
    }
    #pragma unroll
    for (int off = TPR; off < 64; off <<= 1) {
        s.x += __shfl_xor(s.x, off); s.y += __shfl_xor(s.y, off);
        s.z += __shfl_xor(s.z, off); s.w += __shfl_xor(s.w, off);
        q.x += __shfl_xor(q.x, off); q.y += __shfl_xor(q.y, off);
        q.z += __shfl_xor(q.z, off); q.w += __shfl_xor(q.w, off);
    }
    if (lane < TPR) {
        *(float4*)&red[w][cg * 4] = s;
        *(float4*)&red[w][C + cg * 4] = q;
    }
    __syncthreads();
    for (int idx = t; idx < 2 * C; idx += 256) {
        float tot = red[0][idx] + red[1][idx] + red[2][idx] + red[3][idx];
        atomicAdd(&sums[idx], tot);
    }
}

__global__ void k_bnfin(const float* __restrict__ sums, int M, int C,
                        const float* __restrict__ g, const float* __restrict__ b,
                        float* __restrict__ st) {
    int c = threadIdx.x;
    if (c < C) {
        float mu = sums[c] / (float)M;
        float var = sums[C + c] / (float)M - mu * mu;
        float s = g[c] * rsqrtf(var + BN_EPS);
        st[c] = s;
        st[C + c] = b[c] - mu * s;
    }
}

// ---------------- prepass: fp32 -> BN affine (+ELU) -> bf16, C=128 ----------------
__global__ __launch_bounds__(256) void k_prep(const float* __restrict__ in, const float* __restrict__ st,
                                              int M, int elu, unsigned short* __restrict__ outb) {
    int tid = blockIdx.x * 256 + threadIdx.x;
    size_t idx = (size_t)tid * 8;
    if (idx >= (size_t)M * 128) return;
    int ch = (int)(idx & 127);
    float4 v0 = *(const float4*)&in[idx];
    float4 v1 = *(const float4*)&in[idx + 4];
    float4 s0 = *(const float4*)&st[ch];
    float4 s1 = *(const float4*)&st[ch + 4];
    float4 t0 = *(const float4*)&st[128 + ch];
    float4 t1 = *(const float4*)&st[128 + ch + 4];
    float a[8] = {v0.x*s0.x+t0.x, v0.y*s0.y+t0.y, v0.z*s0.z+t0.z, v0.w*s0.w+t0.w,
                  v1.x*s1.x+t1.x, v1.y*s1.y+t1.y, v1.z*s1.z+t1.z, v1.w*s1.w+t1.w};
    if (elu) {
        #pragma unroll
        for (int j = 0; j < 8; j++) a[j] = a[j] > 0.f ? a[j] : expm1f(a[j]);
    }
    uint4 p;
    p.x = ((unsigned)f2bf(a[1]) << 16) | f2bf(a[0]);
    p.y = ((unsigned)f2bf(a[3]) << 16) | f2bf(a[2]);
    p.z = ((unsigned)f2bf(a[5]) << 16) | f2bf(a[4]);
    p.w = ((unsigned)f2bf(a[7]) << 16) | f2bf(a[6]);
    *(uint4*)&outb[idx] = p;
}

// ---------------- W^T bf16 (both layers in one launch) ----------------
__global__ __launch_bounds__(256) void k_wt2(const float* __restrict__ W1, const float* __restrict__ W2,
                                             unsigned short* __restrict__ wt1, unsigned short* __restrict__ wt2) {
    int idx = blockIdx.x * 256 + threadIdx.x;
    if (idx >= 128 * 128) return;
    int n = idx >> 7, k = idx & 127;
    wt1[idx] = f2bf(W1[k * 128 + n]);
    wt2[idx] = f2bf(W2[k * 128 + n]);
}

// ---------------- MFMA GEMM [M,128]@[128,128] -> bf16 hb; epilogue: als/ald dot ----------------
__global__ __launch_bounds__(256) void k_mfma(
    const unsigned short* __restrict__ abf, const unsigned short* __restrict__ wt,
    const float* __restrict__ asrc, const float* __restrict__ adst, int M,
    unsigned short* __restrict__ hb, float* __restrict__ als, float* __restrict__ ald) {
    __shared__ unsigned short As[64 * 136];
    __shared__ unsigned short Bs[128 * 136];
    const int t = threadIdx.x;
    const int w = t >> 6, lane = t & 63;
    const int c = lane & 15, q = lane >> 4;
    const int row0 = blockIdx.x * 64;

    #pragma unroll
    for (int i = 0; i < 4; i++) {
        int idx = t + i * 256;
        int r = idx >> 4, ch = idx & 15;
        uint4 v = make_uint4(0, 0, 0, 0);
        if (row0 + r < M) v = *(const uint4*)&abf[(size_t)(row0 + r) * 128 + ch * 8];
        *(uint4*)&As[r * 136 + ch * 8] = v;
    }
    #pragma unroll
    for (int i = 0; i < 8; i++) {
        int idx = t + i * 256;
        int r = idx >> 4, ch = idx & 15;
        *(uint4*)&Bs[r * 136 + ch * 8] = *(const uint4*)&wt[(size_t)r * 128 + ch * 8];
    }
    __syncthreads();

    f32x4 acc[8] = {};
    #pragma unroll
    for (int ks = 0; ks < 4; ks++) {
        bf16x8 a = *(bf16x8*)&As[(w * 16 + c) * 136 + (ks * 4 + q) * 8];
        #pragma unroll
        for (int tl = 0; tl < 8; tl++) {
            bf16x8 b = *(bf16x8*)&Bs[(tl * 16 + c) * 136 + (ks * 4 + q) * 8];
            acc[tl] = __builtin_amdgcn_mfma_f32_16x16x32_bf16(a, b, acc[tl], 0, 0, 0);
        }
    }

    #pragma unroll
    for (int reg = 0; reg < 4; reg++) {
        int grow = row0 + w * 16 + q * 4 + reg;
        if (grow < M) {
            #pragma unroll
            for (int tl = 0; tl < 8; tl++)
                hb[(size_t)grow * 128 + tl * 16 + c] = f2bf(acc[tl][reg]);
        }
    }

    float as_[8], ad_[8];
    #pragma unroll
    for (int tl = 0; tl < 8; tl++) { as_[tl] = asrc[tl * 16 + c]; ad_[tl] = adst[tl * 16 + c]; }
    #pragma unroll
    for (int reg = 0; reg < 4; reg++) {
        float s0 = 0.f, s1 = 0.f, d0 = 0.f, d1 = 0.f;
        #pragma unroll
        for (int tl = 0; tl < 4; tl++) { s0 += acc[tl][reg] * as_[tl]; d0 += acc[tl][reg] * ad_[tl]; }
        #pragma unroll
        for (int tl = 4; tl < 8; tl++) { s1 += acc[tl][reg] * as_[tl]; d1 += acc[tl][reg] * ad_[tl]; }
        #pragma unroll
        for (int off = 1; off < 16; off <<= 1) {
            s0 += __shfl_xor(s0, off); s1 += __shfl_xor(s1, off);
            d0 += __shfl_xor(d0, off); d1 += __shfl_xor(d1, off);
        }
        int grow = row0 + w * 16 + q * 4 + reg;
        if (c == 0 && grow < M) {
            *(float2*)&als[(size_t)grow * 2] = make_float2(s0, s1);
            *(float2*)&ald[(size_t)grow * 2] = make_float2(d0, d1);
        }
    }
}

// ---------------- fused softmax + aggregation: wave per dst node ----------------
static __device__ __forceinline__ void acc8(float* acc, uint4 v, float a) {
    float2 p;
    p = bf2x2(v.x); acc[0] += a * p.x; acc[1] += a * p.y;
    p = bf2x2(v.y); acc[2] += a * p.x; acc[3] += a * p.y;
    p = bf2x2(v.z); acc[4] += a * p.x; acc[5] += a * p.y;
    p = bf2x2(v.w); acc[6] += a * p.x; acc[7] += a * p.y;
}

template <int MEAN>
static __device__ __forceinline__ void attnagg(
    const int* __restrict__ rowptr, const int* __restrict__ ssrc,
    const float* __restrict__ als, const float* __restrict__ ald,
    float* __restrict__ alpha, const unsigned short* __restrict__ hb,
    const float* __restrict__ bias, int Nn, float* __restrict__ out) {
    int gw = (blockIdx.x * blockDim.x + threadIdx.x) >> 6;
    if (gw >= Nn) return;
    int lane = threadIdx.x & 63;
    int sub = lane >> 4, c = lane & 15, head = c >> 3;
    int beg = rowptr[gw], end = rowptr[gw + 1];
    int deg = end - beg;
    float2 dv = *(const float2*)&ald[(size_t)gw * 2];
    float acc[8] = {};

    if (deg <= 64) {
        bool on = lane < deg;
        int eidx = beg + (on ? lane : 0);
        int sreg = ssrc[eidx];
        float2 av = *(const float2*)&als[(size_t)sreg * 2];
        float v0 = av.x + dv.x; v0 = v0 > 0.f ? v0 : NEG_SLOPE * v0;
        float v1 = av.y + dv.y; v1 = v1 > 0.f ? v1 : NEG_SLOPE * v1;
        float m0 = on ? v0 : -1e30f, m1 = on ? v1 : -1e30f;
        #pragma unroll
        for (int off = 32; off; off >>= 1) {
            m0 = fmaxf(m0, __shfl_xor(m0, off));
            m1 = fmaxf(m1, __shfl_xor(m1, off));
        }
        float p0 = on ? __expf(v0 - m0) : 0.f;
        float p1 = on ? __expf(v1 - m1) : 0.f;
        float t0 = p0, t1 = p1;
        #pragma unroll
        for (int off = 32; off; off >>= 1) {
            t0 += __shfl_xor(t0, off);
            t1 += __shfl_xor(t1, off);
        }
        float al0 = p0 / t0, al1 = p1 / t1;

        // pass 2: uniform trip count, 4 gathers in flight per lane
        int nit = (deg + 3) >> 2;                 // wave-uniform
        for (int it = 0; it < nit; it += 4) {
            #pragma unroll
            for (int u = 0; u < 4; u++) {
                int jj = (it + u) * 4 + sub;
                int ls = jj & 63;
                int sa = __shfl(sreg, ls);
                float a0 = __shfl(al0, ls);
                float a1 = __shfl(al1, ls);
                float aa = head ? a1 : a0;
                if (jj < deg) {
                    uint4 v = *(const uint4*)&hb[(size_t)sa * 128 + c * 8];
                    acc8(acc, v, aa);
                }
            }
        }
    } else {
        // fallback (deg > 64): alpha via global buffer
        float d0 = dv.x, d1 = dv.y;
        float m0 = -1e30f, m1 = -1e30f;
        for (int e = beg + lane; e < end; e += 64) {
            int s = ssrc[e];
            float v0 = als[s * 2] + d0;     v0 = v0 > 0.f ? v0 : NEG_SLOPE * v0;
            float v1 = als[s * 2 + 1] + d1; v1 = v1 > 0.f ? v1 : NEG_SLOPE * v1;
            m0 = fmaxf(m0, v0); m1 = fmaxf(m1, v1);
        }
        #pragma unroll
        for (int off = 32; off; off >>= 1) {
            m0 = fmaxf(m0, __shfl_xor(m0, off));
            m1 = fmaxf(m1, __shfl_xor(m1, off));
        }
        float t0 = 0.f, t1 = 0.f;
        for (int e = beg + lane; e < end; e += 64) {
            int s = ssrc[e];
            float v0 = als[s * 2] + d0;     v0 = v0 > 0.f ? v0 : NEG_SLOPE * v0;
            float v1 = als[s * 2 + 1] + d1; v1 = v1 > 0.f ? v1 : NEG_SLOPE * v1;
            float p0 = __expf(v0 - m0), p1 = __expf(v1 - m1);
            alpha[e * 2] = p0; alpha[e * 2 + 1] = p1;
            t0 += p0; t1 += p1;
        }
        #pragma unroll
        for (int off = 32; off; off >>= 1) {
            t0 += __shfl_xor(t0, off);
            t1 += __shfl_xor(t1, off);
        }
        float i0 = 1.f / t0, i1 = 1.f / t1;
        for (int e = beg + sub; e < end; e += 4) {
            int s = ssrc[e];
            float a = (head ? alpha[(size_t)e * 2 + 1] * i1 : alpha[(size_t)e * 2] * i0);
            uint4 v = *(const uint4*)&hb[(size_t)s * 128 + c * 8];
            acc8(acc, v, a);
        }
    }

    #pragma unroll
    for (int j2 = 0; j2 < 8; j2++) {
        acc[j2] += __shfl_xor(acc[j2], 16);
        acc[j2] += __shfl_xor(acc[j2], 32);
        if (MEAN) acc[j2] += __shfl_xor(acc[j2], 8);
    }
    if (MEAN) {
        if (sub == 0 && c < 8) {
            float4 b0 = *(const float4*)&bias[c * 8];
            float4 b1 = *(const float4*)&bias[c * 8 + 4];
            float4 o0 = make_float4(0.5f * acc[0] + b0.x, 0.5f * acc[1] + b0.y, 0.5f * acc[2] + b0.z, 0.5f * acc[3] + b0.w);
            float4 o1 = make_float4(0.5f * acc[4] + b1.x, 0.5f * acc[5] + b1.y, 0.5f * acc[6] + b1.z, 0.5f * acc[7] + b1.w);
            *(float4*)&out[(size_t)gw * 64 + c * 8] = o0;
            *(float4*)&out[(size_t)gw * 64 + c * 8 + 4] = o1;
        }
    } else {
        if (sub == 0) {
            float4 b0 = *(const float4*)&bias[c * 8];
            float4 b1 = *(const float4*)&bias[c * 8 + 4];
            float4 o0 = make_float4(acc[0] + b0.x, acc[1] + b0.y, acc[2] + b0.z, acc[3] + b0.w);
            float4 o1 = make_float4(acc[4] + b1.x, acc[5] + b1.y, acc[6] + b1.z, acc[7] + b1.w);
            *(float4*)&out[(size_t)gw * 128 + c * 8] = o0;
            *(float4*)&out[(size_t)gw * 128 + c * 8 + 4] = o1;
        }
    }
}

__global__ __launch_bounds__(256) void k_attnagg1(const int* __restrict__ rowptr, const int* __restrict__ ssrc,
                                                  const float* __restrict__ als, const float* __restrict__ ald,
                                                  float* __restrict__ alpha, const unsigned short* __restrict__ hb,
                                                  const float* __restrict__ bias, int Nn, float* __restrict__ out) {
    attnagg<0>(rowptr, ssrc, als, ald, alpha, hb, bias, Nn, out);
}

__global__ __launch_bounds__(256) void k_attnagg2(const int* __restrict__ rowptr, const int* __restrict__ ssrc,
                                                  const float* __restrict__ als, const float* __restrict__ ald,
                                                  float* __restrict__ alpha, const unsigned short* __restrict__ hb,
                                                  const float* __restrict__ bias, int Nn, float* __restrict__ out) {
    attnagg<1>(rowptr, ssrc, als, ald, alpha, hb, bias, Nn, out);
}

// ---------------- final GEMM [M,64] @ [64,40] + bias, BN affine + ELU fused on A ----------------
__global__ __launch_bounds__(128) void k_gemmf(const float* __restrict__ A, const float* __restrict__ Wf,
                                               const float* __restrict__ bf, const float* __restrict__ st,
                                               int M, float* __restrict__ out) {
    __shared__ float As[128 * 65];
    __shared__ float Bs[64 * 40];
    int t = threadIdx.x;
    int row0 = blockIdx.x * 128;
    for (int i = t; i < 64 * 40; i += 128) Bs[i] = Wf[i];
    for (int i = t; i < 128 * 64; i += 128) {
        int r = i >> 6, k = i & 63;
        int gr = row0 + r;
        float v = 0.f;
        if (gr < M) {
            v = A[(size_t)gr * 64 + k] * st[k] + st[64 + k];
            v = v > 0.f ? v : expm1f(v);
        }
        As[r * 65 + k] = v;
    }
    __syncthreads();
    int cg = t & 3, rg = t >> 2;
    float acc[4][10] = {};
    for (int k = 0; k < 64; k++) {
        float b[10];
        #pragma unroll
        for (int j = 0; j < 10; j++) b[j] = Bs[k * 40 + cg * 10 + j];
        #pragma unroll
        for (int r = 0; r < 4; r++) {
            float a = As[(rg * 4 + r) * 65 + k];
            #pragma unroll
            for (int j = 0; j < 10; j++) acc[r][j] += a * b[j];
        }
    }
    for (int r = 0; r < 4; r++) {
        int gr = row0 + rg * 4 + r;
        if (gr < M) {
            #pragma unroll
            for (int j = 0; j < 10; j++) out[(size_t)gr * 40 + cg * 10 + j] = acc[r][j] + bf[cg * 10 + j];
        }
    }
}

extern "C" void kernel_launch(void* const* d_in, const int* in_sizes, int n_in,
                              void* d_out, int out_size, void* d_ws, size_t ws_size,
                              hipStream_t stream) {
    const float* x     = (const float*)d_in[0];
    const int*   ei    = (const int*)d_in[1];
    const float* bn0_g = (const float*)d_in[2];
    const float* bn0_b = (const float*)d_in[3];
    const float* W1    = (const float*)d_in[4];
    const float* a1s   = (const float*)d_in[5];
    const float* a1d   = (const float*)d_in[6];
    const float* b1    = (const float*)d_in[7];
    const float* bn1_g = (const float*)d_in[8];
    const float* bn1_b = (const float*)d_in[9];
    const float* W2    = (const float*)d_in[10];
    const float* a2s   = (const float*)d_in[11];
    const float* a2d   = (const float*)d_in[12];
    const float* b2    = (const float*)d_in[13];
    const float* bn2_g = (const float*)d_in[14];
    const float* bn2_b = (const float*)d_in[15];
    const float* Wf    = (const float*)d_in[16];
    const float* bf    = (const float*)d_in[17];
    float* out = (float*)d_out;

    const int N  = in_sizes[0] / 128;
    const int E  = in_sizes[1] / 2;
    const int ET = E + N;

    char* ws = (char*)d_ws;
    size_t off = 0;
    auto alloc = [&](size_t bytes) -> char* {
        char* p = ws + off;
        off = (off + bytes + 255) & ~(size_t)255;
        return p;
    };
    int*   cnt    = (int*)alloc((size_t)N * 4);
    int*   rowptr = (int*)alloc((size_t)(N + 1) * 4);
    int*   ssrc   = (int*)alloc((size_t)ET * 4);
    float* abuf   = (float*)alloc((size_t)N * 128 * 4);
    unsigned short* abf = (unsigned short*)alloc((size_t)N * 128 * 2);
    unsigned short* hb  = (unsigned short*)alloc((size_t)N * 128 * 2);
    unsigned short* wt1 = (unsigned short*)alloc((size_t)128 * 128 * 2);
    unsigned short* wt2 = (unsigned short*)alloc((size_t)128 * 128 * 2);
    float* als    = (float*)alloc((size_t)N * 2 * 4);
    float* ald    = (float*)alloc((size_t)N * 2 * 4);
    int*   part   = (int*)alloc(1024 * 4);
    float* sums   = (float*)alloc(640 * 4);      // BN0:0, BN1:+256, BN2:+512
    float* st     = (float*)alloc(256 * 4);
    // aliases into dead regions (stream-ordered safety):
    int*   rank   = (int*)hb;     // live k_rank -> k_fill2; hb written at k_mfma
    float* alpha  = (float*)abf;  // deg>64 fallback only; abf dead inside attnagg

    const int tb = 256;
    const int egrid = (ET + tb - 1) / tb;
    const int wgrid = ((size_t)N * 64 + tb - 1) / tb;
    const int pgrid = ((size_t)N * 16 + tb - 1) / tb;
    const int ggrid = (N + 63) / 64;
    const int nscan = (N + 1023) / 1024;
    const int bgrid = (N + 255) / 256;           // bnstat2 (256 rows/block)

    // CSR build
    hipMemsetAsync(cnt, 0, (size_t)N * 4, stream);
    hipMemsetAsync(sums, 0, 640 * 4, stream);
    k_rank<<<egrid, tb, 0, stream>>>(ei, E, N, cnt, rank);
    k_part<<<nscan, 1024, 0, stream>>>(cnt, N, part);
    k_scanp<<<1, 64, 0, stream>>>(part, nscan, N, rowptr);
    k_scan2<<<nscan, 1024, 0, stream>>>(cnt, N, part, rowptr);
    k_fill2<<<egrid, tb, 0, stream>>>(ei, rank, rowptr, E, N, ssrc);

    // weights (independent of CSR/BN)
    k_wt2<<<64, tb, 0, stream>>>(W1, W2, wt1, wt2);

    // BN0
    k_bnstat2<128><<<bgrid, 256, 0, stream>>>(x, N, 256, sums);
    k_bnfin<<<1, 128, 0, stream>>>(sums, N, 128, bn0_g, bn0_b, st);

    // layer 1
    k_prep<<<pgrid, tb, 0, stream>>>(x, st, N, 0, abf);
    k_mfma<<<ggrid, tb, 0, stream>>>(abf, wt1, a1s, a1d, N, hb, als, ald);
    k_attnagg1<<<wgrid, tb, 0, stream>>>(rowptr, ssrc, als, ald, alpha, hb, b1, N, abuf);

    // BN1
    k_bnstat2<128><<<bgrid, 256, 0, stream>>>(abuf, N, 256, sums + 256);
    k_bnfin<<<1, 128, 0, stream>>>(sums + 256, N, 128, bn1_g, bn1_b, st);

    // layer 2
    k_prep<<<pgrid, tb, 0, stream>>>(abuf, st, N, 1, abf);
    k_mfma<<<ggrid, tb, 0, stream>>>(abf, wt2, a2s, a2d, N, hb, als, ald);
    k_attnagg2<<<wgrid, tb, 0, stream>>>(rowptr, ssrc, als, ald, alpha, hb, b2, N, abuf);

    // BN2
    k_bnstat2<64><<<bgrid, 256, 0, stream>>>(abuf, N, 256, sums + 512);
    k_bnfin<<<1, 64, 0, stream>>>(sums + 512, N, 64, bn2_g, bn2_b, st);

    // final linear
    k_gemmf<<<(N + 127) / 128, 128, 0, stream>>>(abuf, Wf, bf, st, N, out);
}

// Round 8
// 340.400 us; speedup vs baseline: 2.2437x; 1.0022x over previous
//
#include <hip/hip_runtime.h>
#include <hip/hip_fp16.h>

// GAT 2-layer + BN + final linear on MI355X.
// R8: k_prep fused into k_mfma A-staging (BN affine + ELU + bf16 cvt on the
// fly; abf buffer gone). attnagg: unroll-2 (R7's unroll-4 regressed) and
// alpha distributed as one packed fp16x2 shfl (2 bpermutes/edge, was 3).

#define NEG_SLOPE 0.2f
#define BN_EPS 1e-5f

typedef short bf16x8 __attribute__((ext_vector_type(8)));
typedef float f32x4 __attribute__((ext_vector_type(4)));

static __device__ __forceinline__ unsigned short f2bf(float f) {
    union { float f; unsigned u; } v; v.f = f;
    unsigned r = v.u + 0x7FFF + ((v.u >> 16) & 1);
    return (unsigned short)(r >> 16);
}
static __device__ __forceinline__ float2 bf2x2(unsigned v) {
    union { unsigned u; float f; } a, b;
    a.u = v << 16; b.u = v & 0xffff0000u;
    return make_float2(a.f, b.f);
}
static __device__ __forceinline__ float halfsel(unsigned p, int head) {
    __half2 h = *(__half2*)&p;
    return head ? __high2float(h) : __low2float(h);
}

// ---------------- CSR build ----------------
__global__ void k_rank(const int* __restrict__ ei, int E, int Nn,
                       int* __restrict__ cnt, int* __restrict__ rank) {
    int i = blockIdx.x * blockDim.x + threadIdx.x;
    if (i >= E + Nn) return;
    int d = (i < E) ? ei[E + i] : (i - E);
    rank[i] = atomicAdd(&cnt[d], 1);
}

__global__ __launch_bounds__(1024) void k_part(const int* __restrict__ cnt, int Nn,
                                               int* __restrict__ part) {
    __shared__ int ws[16];
    int t = threadIdx.x, lane = t & 63, w = t >> 6;
    int i = blockIdx.x * 1024 + t;
    int v = (i < Nn) ? cnt[i] : 0;
    #pragma unroll
    for (int off = 32; off; off >>= 1) v += __shfl_xor(v, off);
    if (lane == 0) ws[w] = v;
    __syncthreads();
    if (t < 16) {
        int s = ws[t];
        #pragma unroll
        for (int off = 8; off; off >>= 1) s += __shfl_xor(s, off);
        if (t == 0) part[blockIdx.x] = s;
    }
}

__global__ __launch_bounds__(64) void k_scanp(int* __restrict__ part, int nb,
                                              int Nn, int* __restrict__ rowptr) {
    int lane = threadIdx.x;
    int carry = 0;
    for (int base = 0; base < nb; base += 64) {
        int i = base + lane;
        int v = (i < nb) ? part[i] : 0;
        int x = v;
        #pragma unroll
        for (int off = 1; off < 64; off <<= 1) {
            int y = __shfl_up(x, off);
            if (lane >= off) x += y;
        }
        if (i < nb) part[i] = carry + x - v;
        carry += __shfl(x, 63);
    }
    if (lane == 0) rowptr[Nn] = carry;
}

__global__ __launch_bounds__(1024) void k_scan2(const int* __restrict__ cnt, int Nn,
                                                const int* __restrict__ part,
                                                int* __restrict__ rowptr) {
    __shared__ int wsum[16];
    int t = threadIdx.x, lane = t & 63, w = t >> 6;
    int i = blockIdx.x * 1024 + t;
    int v = (i < Nn) ? cnt[i] : 0;
    int x = v;
    #pragma unroll
    for (int off = 1; off < 64; off <<= 1) {
        int y = __shfl_up(x, off);
        if (lane >= off) x += y;
    }
    if (lane == 63) wsum[w] = x;
    __syncthreads();
    if (w == 0) {
        int val = (lane < 16) ? wsum[lane] : 0;
        int xs = val;
        #pragma unroll
        for (int off = 1; off < 16; off <<= 1) {
            int y = __shfl_up(xs, off);
            if (lane >= off) xs += y;
        }
        if (lane < 16) wsum[lane] = xs - val;
    }
    __syncthreads();
    if (i < Nn) rowptr[i] = part[blockIdx.x] + wsum[w] + (x - v);
}

__global__ void k_fill2(const int* __restrict__ ei, const int* __restrict__ rank,
                        const int* __restrict__ rowptr, int E, int Nn,
                        int* __restrict__ ssrc) {
    int i = blockIdx.x * blockDim.x + threadIdx.x;
    if (i >= E + Nn) return;
    int s, d;
    if (i < E) { s = ei[i]; d = ei[E + i]; }
    else       { s = i - E; d = s; }
    ssrc[rowptr[d] + rank[i]] = s;
}

// ---------------- BatchNorm stats: vectorized streaming ----------------
template <int C>
__global__ __launch_bounds__(256) void k_bnstat2(const float* __restrict__ x, int M,
                                                 int rowsPerBlock, float* __restrict__ sums) {
    constexpr int TPR = C / 4;
    constexpr int RS  = 256 / TPR;
    __shared__ float red[4][2 * C];
    const int t = threadIdx.x;
    const int cg = t % TPR, rg = t / TPR, w = t >> 6, lane = t & 63;
    int r0 = blockIdx.x * rowsPerBlock + rg;
    int r1 = min(M, blockIdx.x * rowsPerBlock + rowsPerBlock);
    float4 s = make_float4(0, 0, 0, 0), q = make_float4(0, 0, 0, 0);
    #pragma unroll 4
    for (int r = r0; r < r1; r += RS) {
        float4 v = *(const float4*)&x[(size_t)r * C + cg * 4];
        s.x += v.x; s.y += v.y; s.z += v.z; s.w += v.w;
        q.x += v.x * v.x; q.y += v.y * v.y; q.z += v.z * v.z; q.w += v.w * v.w;
    }
    #pragma unroll
    for (int off = TPR; off < 64; off <<= 1) {
        s.x += __shfl_xor(s.x, off); s.y += __shfl_xor(s.y, off);
        s.z += __shfl_xor(s.z, off); s.w += __shfl_xor(s.w, off);
        q.x += __shfl_xor(q.x, off); q.y += __shfl_xor(q.y, off);
        q.z += __shfl_xor(q.z, off); q.w += __shfl_xor(q.w, off);
    }
    if (lane < TPR) {
        *(float4*)&red[w][cg * 4] = s;
        *(float4*)&red[w][C + cg * 4] = q;
    }
    __syncthreads();
    for (int idx = t; idx < 2 * C; idx += 256) {
        float tot = red[0][idx] + red[1][idx] + red[2][idx] + red[3][idx];
        atomicAdd(&sums[idx], tot);
    }
}

__global__ void k_bnfin(const float* __restrict__ sums, int M, int C,
                        const float* __restrict__ g, const float* __restrict__ b,
                        float* __restrict__ st) {
    int c = threadIdx.x;
    if (c < C) {
        float mu = sums[c] / (float)M;
        float var = sums[C + c] / (float)M - mu * mu;
        float s = g[c] * rsqrtf(var + BN_EPS);
        st[c] = s;
        st[C + c] = b[c] - mu * s;
    }
}

// ---------------- W^T bf16 (both layers in one launch) ----------------
__global__ __launch_bounds__(256) void k_wt2(const float* __restrict__ W1, const float* __restrict__ W2,
                                             unsigned short* __restrict__ wt1, unsigned short* __restrict__ wt2) {
    int idx = blockIdx.x * 256 + threadIdx.x;
    if (idx >= 128 * 128) return;
    int n = idx >> 7, k = idx & 127;
    wt1[idx] = f2bf(W1[k * 128 + n]);
    wt2[idx] = f2bf(W2[k * 128 + n]);
}

// ---------------- MFMA GEMM [M,128]@[128,128], BN affine(+ELU)+cvt fused in A staging ----------------
__global__ __launch_bounds__(256) void k_mfma(
    const float* __restrict__ A, const unsigned short* __restrict__ wt,
    const float* __restrict__ stp, int elu,
    const float* __restrict__ asrc, const float* __restrict__ adst, int M,
    unsigned short* __restrict__ hb, float* __restrict__ als, float* __restrict__ ald) {
    __shared__ unsigned short As[64 * 136];
    __shared__ unsigned short Bs[128 * 136];
    const int t = threadIdx.x;
    const int w = t >> 6, lane = t & 63;
    const int c = lane & 15, q = lane >> 4;
    const int row0 = blockIdx.x * 64;

    // A tile: 64 rows x 128 ch fp32 -> affine(+ELU) -> bf16 LDS
    #pragma unroll
    for (int i = 0; i < 8; i++) {
        int idx = t + i * 256;                 // 0..2047
        int r = idx >> 5, ch4 = idx & 31;      // row, chunk of 4 channels
        int gr = row0 + r;
        float4 v = make_float4(0, 0, 0, 0);
        if (gr < M) {
            v = *(const float4*)&A[(size_t)gr * 128 + ch4 * 4];
            float4 sc = *(const float4*)&stp[ch4 * 4];
            float4 sh = *(const float4*)&stp[128 + ch4 * 4];
            v.x = v.x * sc.x + sh.x; v.y = v.y * sc.y + sh.y;
            v.z = v.z * sc.z + sh.z; v.w = v.w * sc.w + sh.w;
            if (elu) {
                v.x = v.x > 0.f ? v.x : expm1f(v.x);
                v.y = v.y > 0.f ? v.y : expm1f(v.y);
                v.z = v.z > 0.f ? v.z : expm1f(v.z);
                v.w = v.w > 0.f ? v.w : expm1f(v.w);
            }
        }
        unsigned p0 = ((unsigned)f2bf(v.y) << 16) | f2bf(v.x);
        unsigned p1 = ((unsigned)f2bf(v.w) << 16) | f2bf(v.z);
        *(uint2*)&As[r * 136 + ch4 * 4] = make_uint2(p0, p1);
    }
    #pragma unroll
    for (int i = 0; i < 8; i++) {
        int idx = t + i * 256;
        int r = idx >> 4, ch = idx & 15;
        *(uint4*)&Bs[r * 136 + ch * 8] = *(const uint4*)&wt[(size_t)r * 128 + ch * 8];
    }
    __syncthreads();

    f32x4 acc[8] = {};
    #pragma unroll
    for (int ks = 0; ks < 4; ks++) {
        bf16x8 a = *(bf16x8*)&As[(w * 16 + c) * 136 + (ks * 4 + q) * 8];
        #pragma unroll
        for (int tl = 0; tl < 8; tl++) {
            bf16x8 b = *(bf16x8*)&Bs[(tl * 16 + c) * 136 + (ks * 4 + q) * 8];
            acc[tl] = __builtin_amdgcn_mfma_f32_16x16x32_bf16(a, b, acc[tl], 0, 0, 0);
        }
    }

    // epilogue 1: bf16 h store. C/D: col = c, row = q*4 + reg.
    #pragma unroll
    for (int reg = 0; reg < 4; reg++) {
        int grow = row0 + w * 16 + q * 4 + reg;
        if (grow < M) {
            #pragma unroll
            for (int tl = 0; tl < 8; tl++)
                hb[(size_t)grow * 128 + tl * 16 + c] = f2bf(acc[tl][reg]);
        }
    }

    // epilogue 2: attention logits als/ald
    float as_[8], ad_[8];
    #pragma unroll
    for (int tl = 0; tl < 8; tl++) { as_[tl] = asrc[tl * 16 + c]; ad_[tl] = adst[tl * 16 + c]; }
    #pragma unroll
    for (int reg = 0; reg < 4; reg++) {
        float s0 = 0.f, s1 = 0.f, d0 = 0.f, d1 = 0.f;
        #pragma unroll
        for (int tl = 0; tl < 4; tl++) { s0 += acc[tl][reg] * as_[tl]; d0 += acc[tl][reg] * ad_[tl]; }
        #pragma unroll
        for (int tl = 4; tl < 8; tl++) { s1 += acc[tl][reg] * as_[tl]; d1 += acc[tl][reg] * ad_[tl]; }
        #pragma unroll
        for (int off = 1; off < 16; off <<= 1) {
            s0 += __shfl_xor(s0, off); s1 += __shfl_xor(s1, off);
            d0 += __shfl_xor(d0, off); d1 += __shfl_xor(d1, off);
        }
        int grow = row0 + w * 16 + q * 4 + reg;
        if (c == 0 && grow < M) {
            *(float2*)&als[(size_t)grow * 2] = make_float2(s0, s1);
            *(float2*)&ald[(size_t)grow * 2] = make_float2(d0, d1);
        }
    }
}

// ---------------- fused softmax + aggregation: wave per dst node ----------------
static __device__ __forceinline__ void acc8(float* acc, uint4 v, float a) {
    float2 p;
    p = bf2x2(v.x); acc[0] += a * p.x; acc[1] += a * p.y;
    p = bf2x2(v.y); acc[2] += a * p.x; acc[3] += a * p.y;
    p = bf2x2(v.z); acc[4] += a * p.x; acc[5] += a * p.y;
    p = bf2x2(v.w); acc[6] += a * p.x; acc[7] += a * p.y;
}

template <int MEAN>
static __device__ __forceinline__ void attnagg(
    const int* __restrict__ rowptr, const int* __restrict__ ssrc,
    const float* __restrict__ als, const float* __restrict__ ald,
    float* __restrict__ alpha, const unsigned short* __restrict__ hb,
    const float* __restrict__ bias, int Nn, float* __restrict__ out) {
    int gw = (blockIdx.x * blockDim.x + threadIdx.x) >> 6;
    if (gw >= Nn) return;
    int lane = threadIdx.x & 63;
    int sub = lane >> 4, c = lane & 15, head = c >> 3;
    int beg = rowptr[gw], end = rowptr[gw + 1];
    int deg = end - beg;
    float2 dv = *(const float2*)&ald[(size_t)gw * 2];
    float acc[8] = {};

    if (deg <= 64) {
        bool on = lane < deg;
        int eidx = beg + (on ? lane : 0);
        int sreg = ssrc[eidx];
        float2 av = *(const float2*)&als[(size_t)sreg * 2];
        float v0 = av.x + dv.x; v0 = v0 > 0.f ? v0 : NEG_SLOPE * v0;
        float v1 = av.y + dv.y; v1 = v1 > 0.f ? v1 : NEG_SLOPE * v1;
        float m0 = on ? v0 : -1e30f, m1 = on ? v1 : -1e30f;
        #pragma unroll
        for (int off = 32; off; off >>= 1) {
            m0 = fmaxf(m0, __shfl_xor(m0, off));
            m1 = fmaxf(m1, __shfl_xor(m1, off));
        }
        float p0 = on ? __expf(v0 - m0) : 0.f;
        float p1 = on ? __expf(v1 - m1) : 0.f;
        float t0 = p0, t1 = p1;
        #pragma unroll
        for (int off = 32; off; off >>= 1) {
            t0 += __shfl_xor(t0, off);
            t1 += __shfl_xor(t1, off);
        }
        // pack normalized alphas as fp16x2 -> ONE shfl distributes both heads
        __half2 hpk = __floats2half2_rn(p0 / t0, p1 / t1);
        int pk = *(int*)&hpk;

        // pass 2: uniform trip count, 2 gathers in flight per lane
        int nit = (deg + 3) >> 2;                 // wave-uniform
        for (int it = 0; it < nit; it += 2) {
            int j0 = it * 4 + sub;
            int j1 = j0 + 4;
            int sa = __shfl(sreg, j0 & 63);
            int sb = __shfl(sreg, j1 & 63);
            unsigned pa = (unsigned)__shfl(pk, j0 & 63);
            unsigned pb = (unsigned)__shfl(pk, j1 & 63);
            float aa = halfsel(pa, head);
            float ab = halfsel(pb, head);
            if (j0 < deg) {
                uint4 va = *(const uint4*)&hb[(size_t)sa * 128 + c * 8];
                acc8(acc, va, aa);
            }
            if (j1 < deg) {
                uint4 vb = *(const uint4*)&hb[(size_t)sb * 128 + c * 8];
                acc8(acc, vb, ab);
            }
        }
    } else {
        // fallback (deg > 64): alpha via global buffer
        float d0 = dv.x, d1 = dv.y;
        float m0 = -1e30f, m1 = -1e30f;
        for (int e = beg + lane; e < end; e += 64) {
            int s = ssrc[e];
            float v0 = als[s * 2] + d0;     v0 = v0 > 0.f ? v0 : NEG_SLOPE * v0;
            float v1 = als[s * 2 + 1] + d1; v1 = v1 > 0.f ? v1 : NEG_SLOPE * v1;
            m0 = fmaxf(m0, v0); m1 = fmaxf(m1, v1);
        }
        #pragma unroll
        for (int off = 32; off; off >>= 1) {
            m0 = fmaxf(m0, __shfl_xor(m0, off));
            m1 = fmaxf(m1, __shfl_xor(m1, off));
        }
        float t0 = 0.f, t1 = 0.f;
        for (int e = beg + lane; e < end; e += 64) {
            int s = ssrc[e];
            float v0 = als[s * 2] + d0;     v0 = v0 > 0.f ? v0 : NEG_SLOPE * v0;
            float v1 = als[s * 2 + 1] + d1; v1 = v1 > 0.f ? v1 : NEG_SLOPE * v1;
            float p0 = __expf(v0 - m0), p1 = __expf(v1 - m1);
            alpha[e * 2] = p0; alpha[e * 2 + 1] = p1;
            t0 += p0; t1 += p1;
        }
        #pragma unroll
        for (int off = 32; off; off >>= 1) {
            t0 += __shfl_xor(t0, off);
            t1 += __shfl_xor(t1, off);
        }
        float i0 = 1.f / t0, i1 = 1.f / t1;
        for (int e = beg + sub; e < end; e += 4) {
            int s = ssrc[e];
            float a = (head ? alpha[(size_t)e * 2 + 1] * i1 : alpha[(size_t)e * 2] * i0);
            uint4 v = *(const uint4*)&hb[(size_t)s * 128 + c * 8];
            acc8(acc, v, a);
        }
    }

    #pragma unroll
    for (int j2 = 0; j2 < 8; j2++) {
        acc[j2] += __shfl_xor(acc[j2], 16);
        acc[j2] += __shfl_xor(acc[j2], 32);
        if (MEAN) acc[j2] += __shfl_xor(acc[j2], 8);
    }
    if (MEAN) {
        if (sub == 0 && c < 8) {
            float4 b0 = *(const float4*)&bias[c * 8];
            float4 b1 = *(const float4*)&bias[c * 8 + 4];
            float4 o0 = make_float4(0.5f * acc[0] + b0.x, 0.5f * acc[1] + b0.y, 0.5f * acc[2] + b0.z, 0.5f * acc[3] + b0.w);
            float4 o1 = make_float4(0.5f * acc[4] + b1.x, 0.5f * acc[5] + b1.y, 0.5f * acc[6] + b1.z, 0.5f * acc[7] + b1.w);
            *(float4*)&out[(size_t)gw * 64 + c * 8] = o0;
            *(float4*)&out[(size_t)gw * 64 + c * 8 + 4] = o1;
        }
    } else {
        if (sub == 0) {
            float4 b0 = *(const float4*)&bias[c * 8];
            float4 b1 = *(const float4*)&bias[c * 8 + 4];
            float4 o0 = make_float4(acc[0] + b0.x, acc[1] + b0.y, acc[2] + b0.z, acc[3] + b0.w);
            float4 o1 = make_float4(acc[4] + b1.x, acc[5] + b1.y, acc[6] + b1.z, acc[7] + b1.w);
            *(float4*)&out[(size_t)gw * 128 + c * 8] = o0;
            *(float4*)&out[(size_t)gw * 128 + c * 8 + 4] = o1;
        }
    }
}

__global__ __launch_bounds__(256) void k_attnagg1(const int* __restrict__ rowptr, const int* __restrict__ ssrc,
                                                  const float* __restrict__ als, const float* __restrict__ ald,
                                                  float* __restrict__ alpha, const unsigned short* __restrict__ hb,
                                                  const float* __restrict__ bias, int Nn, float* __restrict__ out) {
    attnagg<0>(rowptr, ssrc, als, ald, alpha, hb, bias, Nn, out);
}

__global__ __launch_bounds__(256) void k_attnagg2(const int* __restrict__ rowptr, const int* __restrict__ ssrc,
                                                  const float* __restrict__ als, const float* __restrict__ ald,
                                                  float* __restrict__ alpha, const unsigned short* __restrict__ hb,
                                                  const float* __restrict__ bias, int Nn, float* __restrict__ out) {
    attnagg<1>(rowptr, ssrc, als, ald, alpha, hb, bias, Nn, out);
}

// ---------------- final GEMM [M,64] @ [64,40] + bias, BN affine + ELU fused on A ----------------
__global__ __launch_bounds__(128) void k_gemmf(const float* __restrict__ A, const float* __restrict__ Wf,
                                               const float* __restrict__ bf, const float* __restrict__ st,
                                               int M, float* __restrict__ out) {
    __shared__ float As[128 * 65];
    __shared__ float Bs[64 * 40];
    int t = threadIdx.x;
    int row0 = blockIdx.x * 128;
    for (int i = t; i < 64 * 40; i += 128) Bs[i] = Wf[i];
    for (int i = t; i < 128 * 64; i += 128) {
        int r = i >> 6, k = i & 63;
        int gr = row0 + r;
        float v = 0.f;
        if (gr < M) {
            v = A[(size_t)gr * 64 + k] * st[k] + st[64 + k];
            v = v > 0.f ? v : expm1f(v);
        }
        As[r * 65 + k] = v;
    }
    __syncthreads();
    int cg = t & 3, rg = t >> 2;
    float acc[4][10] = {};
    for (int k = 0; k < 64; k++) {
        float b[10];
        #pragma unroll
        for (int j = 0; j < 10; j++) b[j] = Bs[k * 40 + cg * 10 + j];
        #pragma unroll
        for (int r = 0; r < 4; r++) {
            float a = As[(rg * 4 + r) * 65 + k];
            #pragma unroll
            for (int j = 0; j < 10; j++) acc[r][j] += a * b[j];
        }
    }
    for (int r = 0; r < 4; r++) {
        int gr = row0 + rg * 4 + r;
        if (gr < M) {
            #pragma unroll
            for (int j = 0; j < 10; j++) out[(size_t)gr * 40 + cg * 10 + j] = acc[r][j] + bf[cg * 10 + j];
        }
    }
}

extern "C" void kernel_launch(void* const* d_in, const int* in_sizes, int n_in,
                              void* d_out, int out_size, void* d_ws, size_t ws_size,
                              hipStream_t stream) {
    const float* x     = (const float*)d_in[0];
    const int*   ei    = (const int*)d_in[1];
    const float* bn0_g = (const float*)d_in[2];
    const float* bn0_b = (const float*)d_in[3];
    const float* W1    = (const float*)d_in[4];
    const float* a1s   = (const float*)d_in[5];
    const float* a1d   = (const float*)d_in[6];
    const float* b1    = (const float*)d_in[7];
    const float* bn1_g = (const float*)d_in[8];
    const float* bn1_b = (const float*)d_in[9];
    const float* W2    = (const float*)d_in[10];
    const float* a2s   = (const float*)d_in[11];
    const float* a2d   = (const float*)d_in[12];
    const float* b2    = (const float*)d_in[13];
    const float* bn2_g = (const float*)d_in[14];
    const float* bn2_b = (const float*)d_in[15];
    const float* Wf    = (const float*)d_in[16];
    const float* bf    = (const float*)d_in[17];
    float* out = (float*)d_out;

    const int N  = in_sizes[0] / 128;
    const int E  = in_sizes[1] / 2;
    const int ET = E + N;

    char* ws = (char*)d_ws;
    size_t off = 0;
    auto alloc = [&](size_t bytes) -> char* {
        char* p = ws + off;
        off = (off + bytes + 255) & ~(size_t)255;
        return p;
    };
    int*   cnt    = (int*)alloc((size_t)N * 4);
    int*   rowptr = (int*)alloc((size_t)(N + 1) * 4);
    int*   ssrc   = (int*)alloc((size_t)ET * 4);
    float* abuf   = (float*)alloc((size_t)N * 128 * 4);
    unsigned short* hb  = (unsigned short*)alloc((size_t)N * 128 * 2);
    unsigned short* wt1 = (unsigned short*)alloc((size_t)128 * 128 * 2);
    unsigned short* wt2 = (unsigned short*)alloc((size_t)128 * 128 * 2);
    float* alpha  = (float*)alloc((size_t)ET * 2 * 4);   // deg>64 fallback only
    float* als    = (float*)alloc((size_t)N * 2 * 4);
    float* ald    = (float*)alloc((size_t)N * 2 * 4);
    int*   part   = (int*)alloc(1024 * 4);
    float* sums   = (float*)alloc(640 * 4);      // BN0:0, BN1:+256, BN2:+512
    float* st     = (float*)alloc(256 * 4);
    // alias: rank lives k_rank -> k_fill2; hb first written at k_mfma L1
    int*   rank   = (int*)hb;

    const int tb = 256;
    const int egrid = (ET + tb - 1) / tb;
    const int wgrid = ((size_t)N * 64 + tb - 1) / tb;
    const int ggrid = (N + 63) / 64;
    const int nscan = (N + 1023) / 1024;
    const int bgrid = (N + 255) / 256;

    // CSR build
    hipMemsetAsync(cnt, 0, (size_t)N * 4, stream);
    hipMemsetAsync(sums, 0, 640 * 4, stream);
    k_rank<<<egrid, tb, 0, stream>>>(ei, E, N, cnt, rank);
    k_part<<<nscan, 1024, 0, stream>>>(cnt, N, part);
    k_scanp<<<1, 64, 0, stream>>>(part, nscan, N, rowptr);
    k_scan2<<<nscan, 1024, 0, stream>>>(cnt, N, part, rowptr);
    k_fill2<<<egrid, tb, 0, stream>>>(ei, rank, rowptr, E, N, ssrc);

    // weights
    k_wt2<<<64, tb, 0, stream>>>(W1, W2, wt1, wt2);

    // BN0
    k_bnstat2<128><<<bgrid, 256, 0, stream>>>(x, N, 256, sums);
    k_bnfin<<<1, 128, 0, stream>>>(sums, N, 128, bn0_g, bn0_b, st);

    // layer 1 (BN0 affine fused into GEMM A staging)
    k_mfma<<<ggrid, tb, 0, stream>>>(x, wt1, st, 0, a1s, a1d, N, hb, als, ald);
    k_attnagg1<<<wgrid, tb, 0, stream>>>(rowptr, ssrc, als, ald, alpha, hb, b1, N, abuf);

    // BN1
    k_bnstat2<128><<<bgrid, 256, 0, stream>>>(abuf, N, 256, sums + 256);
    k_bnfin<<<1, 128, 0, stream>>>(sums + 256, N, 128, bn1_g, bn1_b, st);

    // layer 2 (BN1 affine + ELU fused into GEMM A staging)
    k_mfma<<<ggrid, tb, 0, stream>>>(abuf, wt2, st, 1, a2s, a2d, N, hb, als, ald);
    k_attnagg2<<<wgrid, tb, 0, stream>>>(rowptr, ssrc, als, ald, alpha, hb, b2, N, abuf);

    // BN2
    k_bnstat2<64><<<bgrid, 256, 0, stream>>>(abuf, N, 256, sums + 512);
    k_bnfin<<<1, 64, 0, stream>>>(sums + 512, N, 64, bn2_g, bn2_b, st);

    // final linear
    k_gemmf<<<(N + 127) / 128, 128, 0, stream>>>(abuf, Wf, bf, st, N, out);
}